// Round 3
// baseline (369.559 us; speedup 1.0000x reference)
//
#include <hip/hip_runtime.h>

typedef unsigned short u16;
typedef unsigned int u32;
typedef __bf16 bf16x4 __attribute__((ext_vector_type(4)));
typedef __bf16 bf16x8 __attribute__((ext_vector_type(8)));
typedef float f32x4 __attribute__((ext_vector_type(4)));

struct __align__(4) U16x2 { u16 x, y; };
struct __align__(8) U16x4 { u16 x, y, z, w; };

#define DEV static __device__ __forceinline__

extern "C" __device__ float __ocml_exp2_f32(float);

DEV u16 f2bf(float f) {
  __bf16 h = (__bf16)f;
  return __builtin_bit_cast(u16, h);
}
DEV float bf2f(u16 u) { return __uint_as_float(((u32)u) << 16); }

DEV void gload16(const void* g, void* l) {
  __builtin_amdgcn_global_load_lds((const __attribute__((address_space(1))) char*)g,
                                   (__attribute__((address_space(3))) char*)l, 16, 0, 0);
}

DEV f32x4 mfma16(bf16x8 a, bf16x8 b, f32x4 c) {
  return __builtin_amdgcn_mfma_f32_16x16x32_bf16(a, b, c, 0, 0, 0);
}

// ---------------------------------------------------------------------------
// x fp32 -> bf16, 4 elems/thread
__global__ __launch_bounds__(256) void cvt_x(const float* __restrict__ x, u16* __restrict__ xb) {
  int i = blockIdx.x * 256 + threadIdx.x;
  float4 v = ((const float4*)x)[i];
  U16x4 o;
  o.x = f2bf(v.x); o.y = f2bf(v.y); o.z = f2bf(v.z); o.w = f2bf(v.w);
  ((U16x4*)xb)[i] = o;
}

// ---------------------------------------------------------------------------
// fp32 [R][C] -> bf16 dst[nOff + c][r] (transposed), ldd = R
__global__ __launch_bounds__(256) void tconv(const float* __restrict__ src, u16* __restrict__ dst,
                                             int C, int nOff, int ldd) {
  __shared__ float t[32][33];
  int bx = blockIdx.x, by = blockIdx.y;
  int tx = threadIdx.x, ty = threadIdx.y;
#pragma unroll
  for (int j = 0; j < 4; ++j)
    t[ty + 8 * j][tx] = src[(size_t)(by * 32 + ty + 8 * j) * C + bx * 32 + tx];
  __syncthreads();
#pragma unroll
  for (int j = 0; j < 4; ++j)
    dst[(size_t)(nOff + bx * 32 + ty + 8 * j) * ldd + by * 32 + tx] = f2bf(t[tx][ty + 8 * j]);
}

// ---------------------------------------------------------------------------
// bf16 qkv v-slice [b*2048+s][2560+kh*64+d] -> Vt[(b*8+kh)*64+d][s]
__global__ __launch_bounds__(256) void vtrans(const u16* __restrict__ qkv, u16* __restrict__ Vt) {
  __shared__ u16 t[32][33];
  int bx = blockIdx.x, by = blockIdx.y, bz = blockIdx.z;
  int tx = threadIdx.x, ty = threadIdx.y;
  int b = bz >> 3, kh = bz & 7;
  const u16* src = qkv + (size_t)(b * 2048 + bx * 32) * 3072 + 2560 + kh * 64 + by * 32;
#pragma unroll
  for (int j = 0; j < 4; ++j) t[ty + 8 * j][tx] = src[(size_t)(ty + 8 * j) * 3072 + tx];
  __syncthreads();
  u16* dst = Vt + ((size_t)bz * 64 + by * 32) * 2048 + bx * 32;
#pragma unroll
  for (int j = 0; j < 4; ++j) dst[(size_t)(ty + 8 * j) * 2048 + tx] = t[tx][ty + 8 * j];
}

// ---------------------------------------------------------------------------
// RoPE on q,k heads of qkv[4096][3072]; writes Q[b][h][s][64] (pre-scaled by
// 0.125*log2(e) so attn softmax runs in the exp2 domain), K[b][kh][s][64].
__global__ __launch_bounds__(256) void rope_qk(const u16* __restrict__ qkv,
                                               const float* __restrict__ fc,
                                               const float* __restrict__ fs,
                                               u16* __restrict__ Qo, u16* __restrict__ Ko) {
  int t = blockIdx.x * 256 + threadIdx.x;  // 5,242,880 total
  int d2 = t & 31;
  int rest = t >> 5;
  int h40 = rest % 40;
  int bs = rest / 40;  // b*2048 + s
  int s = bs & 2047;
  int b = bs >> 11;
  const u16* src;
  u16* dst;
  float qscale;
  if (h40 < 32) {
    src = qkv + (size_t)bs * 3072 + h40 * 64 + 2 * d2;
    dst = Qo + (((size_t)(b * 32 + h40) * 2048 + s) * 64 + 2 * d2);
    qscale = 0.18033688011112042f;  // 0.125 * log2(e)
  } else {
    int kh = h40 - 32;
    src = qkv + (size_t)bs * 3072 + 2048 + kh * 64 + 2 * d2;
    dst = Ko + (((size_t)(b * 8 + kh) * 2048 + s) * 64 + 2 * d2);
    qscale = 1.0f;
  }
  U16x2 v = *(const U16x2*)src;
  float xr = bf2f(v.x), xi = bf2f(v.y);
  float c = fc[s * 32 + d2] * qscale, sn = fs[s * 32 + d2] * qscale;
  U16x2 o;
  o.x = f2bf(xr * c - xi * sn);
  o.y = f2bf(xr * sn + xi * c);
  *(U16x2*)dst = o;
}

// ---------------------------------------------------------------------------
// C[M][N] = A[M][K] * BT[N][K]^T  (bf16 in, OutT out). 128x128 tile, BK=64,
// 4 waves (2x2), swizzled LDS, double-buffered global_load_lds staging.
template <typename OutT>
__global__ __launch_bounds__(256, 2) void gemm_bt(const u16* __restrict__ A,
                                                  const u16* __restrict__ BT,
                                                  OutT* __restrict__ C,
                                                  int M, int N, int K) {
  __shared__ __align__(16) char smem[65536];  // As[2]@0, Bs[2]@32768 (16384 each)
  const int tid = threadIdx.x;
  const int lane = tid & 63;
  const int wm = (tid >> 7) & 1, wn = (tid >> 6) & 1;
  const int tm = blockIdx.y, tn = blockIdx.x;
  const int Kb = K * 2;

  f32x4 acc[4][4];
#pragma unroll
  for (int i = 0; i < 4; ++i)
#pragma unroll
    for (int j = 0; j < 4; ++j) acc[i][j] = (f32x4){0.f, 0.f, 0.f, 0.f};

  const char* Ag = (const char*)A + (size_t)tm * 128 * Kb;
  const char* Bg = (const char*)BT + (size_t)tn * 128 * Kb;

  auto stage = [&](int buf, int t) {
#pragma unroll
    for (int i = 0; i < 4; ++i) {
      int vt = i * 256 + tid;
      int row = vt >> 3;
      int cb = (((vt & 7) << 4) ^ ((row & 7) << 4));
      gload16(Ag + (size_t)row * Kb + t * 128 + cb, smem + buf * 16384 + vt * 16);
      gload16(Bg + (size_t)row * Kb + t * 128 + cb, smem + 32768 + buf * 16384 + vt * 16);
    }
  };

  stage(0, 0);
  int cur = 0;
  const int NT = K >> 6;
  for (int t = 0; t < NT; ++t) {
    __syncthreads();
    if (t + 1 < NT) stage(cur ^ 1, t + 1);
    const char* As = smem + cur * 16384;
    const char* Bs = smem + 32768 + cur * 16384;
#pragma unroll
    for (int ks = 0; ks < 2; ++ks) {
      bf16x8 a[4], b[4];
#pragma unroll
      for (int mf = 0; mf < 4; ++mf) {
        int row = wm * 64 + mf * 16 + (lane & 15);
        int cb = (ks * 64 + ((lane >> 4) << 4)) ^ ((row & 7) << 4);
        a[mf] = *(const bf16x8*)(As + row * 128 + cb);
      }
#pragma unroll
      for (int nf = 0; nf < 4; ++nf) {
        int row = wn * 64 + nf * 16 + (lane & 15);
        int cb = (ks * 64 + ((lane >> 4) << 4)) ^ ((row & 7) << 4);
        b[nf] = *(const bf16x8*)(Bs + row * 128 + cb);
      }
#pragma unroll
      for (int mf = 0; mf < 4; ++mf)
#pragma unroll
        for (int nf = 0; nf < 4; ++nf) acc[mf][nf] = mfma16(a[mf], b[nf], acc[mf][nf]);
    }
    cur ^= 1;
  }
#pragma unroll
  for (int mf = 0; mf < 4; ++mf) {
    int row0 = tm * 128 + wm * 64 + mf * 16 + ((lane >> 4) << 2);
#pragma unroll
    for (int nf = 0; nf < 4; ++nf) {
      int col = tn * 128 + wn * 64 + nf * 16 + (lane & 15);
#pragma unroll
      for (int r = 0; r < 4; ++r) {
        float v = acc[mf][nf][r];
        if constexpr (sizeof(OutT) == 4)
          C[(size_t)(row0 + r) * N + col] = v;
        else
          C[(size_t)(row0 + r) * N + col] = f2bf(v);
      }
    }
  }
}

// ---------------------------------------------------------------------------
// Causal GQA flash attention, wave-autonomous rows.
// Block = (qb, h, b); qb = 15 - blockIdx.x (LPT: heavy blocks dispatch first).
// Q pre-scaled by 0.125*log2(e): softmax in exp2 domain (single v_exp_f32).
// Softmax stats in registers; P tile wave-private LDS; 1 barrier per K/V tile.
__global__ __launch_bounds__(256, 2) void attn(const u16* __restrict__ Q,
                                               const u16* __restrict__ Kt,
                                               const u16* __restrict__ Vt,
                                               u16* __restrict__ O) {
  __shared__ __align__(16) char smem[49152];
  // K dbuf: [0,16384)  V dbuf: [16384,32768)  P: [32768,49152) = [128 rows][128 B]

  const int tid = threadIdx.x, lane = tid & 63, w = tid >> 6;
  const int qb = 15 - blockIdx.x, h = blockIdx.y, b = blockIdx.z;
  const int kh = h >> 2;

  const char* Qg = (const char*)(Q + (((size_t)(b * 32 + h) * 2048 + qb * 128) * 64));
  const char* Kg = (const char*)(Kt + ((size_t)(b * 8 + kh) * 2048 * 64));
  const char* Vg = (const char*)(Vt + ((size_t)(b * 8 + kh) * 64 * 2048));
  u16* Og = O + ((size_t)(b * 2048 + qb * 128) * 2048 + h * 64);

  // Q fragments: rows w*32 + mf2*16 + (lane&15), k-halves ks
  bf16x8 qf[2][2];
#pragma unroll
  for (int mf2 = 0; mf2 < 2; ++mf2)
#pragma unroll
    for (int ks = 0; ks < 2; ++ks) {
      int row = w * 32 + mf2 * 16 + (lane & 15);
      qf[mf2][ks] = *(const bf16x8*)(Qg + row * 128 + ks * 64 + ((lane >> 4) << 4));
    }

  f32x4 acc[2][4];
#pragma unroll
  for (int i = 0; i < 2; ++i)
#pragma unroll
    for (int j = 0; j < 4; ++j) acc[i][j] = (f32x4){0.f, 0.f, 0.f, 0.f};
  float m_r[2][4], l_r[2][4];
#pragma unroll
  for (int i = 0; i < 2; ++i)
#pragma unroll
    for (int r = 0; r < 4; ++r) { m_r[i][r] = -1e30f; l_r[i][r] = 0.f; }

  auto stageKV = [&](int buf, int kt) {
#pragma unroll
    for (int i = 0; i < 2; ++i) {
      int vt = i * 256 + tid;
      int row = vt >> 3;
      int cb = (((vt & 7) << 4) ^ ((row & 7) << 4));
      gload16(Kg + (size_t)(kt * 64 + row) * 128 + cb, smem + buf * 8192 + vt * 16);
      gload16(Vg + (size_t)row * 4096 + kt * 128 + cb, smem + 16384 + buf * 8192 + vt * 16);
    }
  };

  stageKV(0, 0);
  int cur = 0;
  const int nkt = 2 * qb + 2;
  for (int kt = 0; kt < nkt; ++kt) {
    __syncthreads();  // KV[cur] staged (compiler drains vmcnt before barrier)
    if (kt + 1 < nkt) stageKV(cur ^ 1, kt + 1);  // prefetch; drains at next barrier
    const char* Ks = smem + cur * 8192;
    const char* Vs = smem + 16384 + cur * 8192;

    // QK^T: rows w*32+mf2*16.., cols nf*16..  (result already in exp2 domain)
    f32x4 sv[2][4];
#pragma unroll
    for (int i = 0; i < 2; ++i)
#pragma unroll
      for (int j = 0; j < 4; ++j) sv[i][j] = (f32x4){0.f, 0.f, 0.f, 0.f};
    __builtin_amdgcn_s_setprio(1);
#pragma unroll
    for (int ks = 0; ks < 2; ++ks) {
      bf16x8 kf[4];
#pragma unroll
      for (int nf = 0; nf < 4; ++nf) {
        int row = nf * 16 + (lane & 15);
        int cb = (ks * 64 + ((lane >> 4) << 4)) ^ ((row & 7) << 4);
        kf[nf] = *(const bf16x8*)(Ks + row * 128 + cb);
      }
#pragma unroll
      for (int mf2 = 0; mf2 < 2; ++mf2)
#pragma unroll
        for (int nf = 0; nf < 4; ++nf) sv[mf2][nf] = mfma16(qf[mf2][ks], kf[nf], sv[mf2][nf]);
    }
    __builtin_amdgcn_s_setprio(0);

    // causal mask (only the 2 diagonal tiles need it)
    if (kt >= 2 * qb) {
#pragma unroll
      for (int mf2 = 0; mf2 < 2; ++mf2)
#pragma unroll
        for (int nf = 0; nf < 4; ++nf)
#pragma unroll
          for (int r = 0; r < 4; ++r) {
            int qg = qb * 128 + w * 32 + mf2 * 16 + ((lane >> 4) << 2) + r;
            int kg = kt * 64 + nf * 16 + (lane & 15);
            if (kg > qg) sv[mf2][nf][r] = -1e30f;
          }
    }

    // per-16-row-fragment softmax, all in registers (exp2 domain)
#pragma unroll
    for (int mf2 = 0; mf2 < 2; ++mf2) {
      float vm[4];
#pragma unroll
      for (int r = 0; r < 4; ++r)
        vm[r] = fmaxf(fmaxf(sv[mf2][0][r], sv[mf2][1][r]), fmaxf(sv[mf2][2][r], sv[mf2][3][r]));
#pragma unroll
      for (int st = 1; st < 16; st <<= 1)
#pragma unroll
        for (int r = 0; r < 4; ++r) vm[r] = fmaxf(vm[r], __shfl_xor(vm[r], st, 64));
      float mn[4], cr[4];
#pragma unroll
      for (int r = 0; r < 4; ++r) {
        mn[r] = fmaxf(m_r[mf2][r], vm[r]);
        cr[r] = __ocml_exp2_f32(m_r[mf2][r] - mn[r]);
        m_r[mf2][r] = mn[r];
      }
      // P = exp2(S - m_new) -> bf16 into wave-private LDS (swizzled); row sums
      float vs[4] = {0.f, 0.f, 0.f, 0.f};
#pragma unroll
      for (int nf = 0; nf < 4; ++nf)
#pragma unroll
        for (int r = 0; r < 4; ++r) {
          float p = __ocml_exp2_f32(sv[mf2][nf][r] - mn[r]);
          u16 pb = f2bf(p);
          vs[r] += bf2f(pb);
          int prow = w * 32 + mf2 * 16 + ((lane >> 4) << 2) + r;
          int sw = (prow & 7) << 4;
          int c0 = (nf * 16 + (lane & 15)) * 2;
          *(u16*)(smem + 32768 + prow * 128 + (c0 ^ sw)) = pb;
        }
#pragma unroll
      for (int st = 1; st < 16; st <<= 1)
#pragma unroll
        for (int r = 0; r < 4; ++r) vs[r] += __shfl_xor(vs[r], st, 64);
#pragma unroll
      for (int r = 0; r < 4; ++r) l_r[mf2][r] = l_r[mf2][r] * cr[r] + vs[r];
      // rescale O accumulator (same row mapping as sv/acc)
#pragma unroll
      for (int nf = 0; nf < 4; ++nf)
#pragma unroll
        for (int r = 0; r < 4; ++r) acc[mf2][nf][r] *= cr[r];
    }

    // PV: wave-private P rows, shared V tile. No barrier needed (same-wave LDS order).
#pragma unroll
    for (int ks = 0; ks < 2; ++ks) {
      bf16x8 pa[2], vb[4];
#pragma unroll
      for (int mf2 = 0; mf2 < 2; ++mf2) {
        int prow = w * 32 + mf2 * 16 + (lane & 15);
        int cb = (ks * 64 + ((lane >> 4) << 4)) ^ ((prow & 7) << 4);
        pa[mf2] = *(const bf16x8*)(smem + 32768 + prow * 128 + cb);
      }
#pragma unroll
      for (int nf = 0; nf < 4; ++nf) {
        int vrow = nf * 16 + (lane & 15);
        int cb = (ks * 64 + ((lane >> 4) << 4)) ^ ((vrow & 7) << 4);
        vb[nf] = *(const bf16x8*)(Vs + vrow * 128 + cb);
      }
      __builtin_amdgcn_s_setprio(1);
#pragma unroll
      for (int mf2 = 0; mf2 < 2; ++mf2)
#pragma unroll
        for (int nf = 0; nf < 4; ++nf) acc[mf2][nf] = mfma16(pa[mf2], vb[nf], acc[mf2][nf]);
      __builtin_amdgcn_s_setprio(0);
    }
    cur ^= 1;
  }

#pragma unroll
  for (int mf2 = 0; mf2 < 2; ++mf2)
#pragma unroll
    for (int r = 0; r < 4; ++r) {
      int row = w * 32 + mf2 * 16 + ((lane >> 4) << 2) + r;
      float li = 1.f / l_r[mf2][r];
#pragma unroll
      for (int nf = 0; nf < 4; ++nf)
        Og[(size_t)row * 2048 + nf * 16 + (lane & 15)] = f2bf(acc[mf2][nf][r] * li);
    }
}

// ---------------------------------------------------------------------------
extern "C" void kernel_launch(void* const* d_in, const int* in_sizes, int n_in,
                              void* d_out, int out_size, void* d_ws, size_t ws_size,
                              hipStream_t stream) {
  const float* x = (const float*)d_in[0];
  const float* fc = (const float*)d_in[1];
  const float* fs = (const float*)d_in[2];
  const float* wq = (const float*)d_in[3];
  const float* wk = (const float*)d_in[4];
  const float* wv = (const float*)d_in[5];
  const float* wo = (const float*)d_in[6];
  float* out = (float*)d_out;
  char* ws = (char*)d_ws;

  // Compact workspace layout (60 MB total):
  u16* xb    = (u16*)(ws);                 // [4096][2048] 16 MB  (reused as Q)
  u16* qkv   = (u16*)(ws + 16777216);      // [4096][3072] 24 MB  (reused as O)
  u16* woT   = (u16*)(ws + 41943040);      // [2048][2048]  8 MB
  u16* wqkvT = (u16*)(ws + 50331648);      // [3072][2048] 12 MB (dead after QKV GEMM)
  u16* Kbuf  = (u16*)(ws + 50331648);      // [2][8][2048][64] 4 MB (overlays wqkvT)
  u16* Vtb   = (u16*)(ws + 54525952);      // [2][8][64][2048] 4 MB (overlays wqkvT)
  u16* Qbuf = xb;
  u16* Obuf = qkv;

  dim3 tb(32, 8);
  cvt_x<<<dim3(8192), dim3(256), 0, stream>>>(x, xb);
  tconv<<<dim3(64, 64), tb, 0, stream>>>(wq, wqkvT, 2048, 0, 2048);
  tconv<<<dim3(16, 64), tb, 0, stream>>>(wk, wqkvT, 512, 2048, 2048);
  tconv<<<dim3(16, 64), tb, 0, stream>>>(wv, wqkvT, 512, 2560, 2048);
  tconv<<<dim3(64, 64), tb, 0, stream>>>(wo, woT, 2048, 0, 2048);
  gemm_bt<u16><<<dim3(24, 32), dim3(256), 0, stream>>>(xb, wqkvT, qkv, 4096, 3072, 2048);
  rope_qk<<<dim3(20480), dim3(256), 0, stream>>>(qkv, fc, fs, Qbuf, Kbuf);
  vtrans<<<dim3(64, 2, 16), tb, 0, stream>>>(qkv, Vtb);
  attn<<<dim3(16, 32, 2), dim3(256), 0, stream>>>(Qbuf, Kbuf, Vtb, Obuf);
  gemm_bt<float><<<dim3(16, 32), dim3(256), 0, stream>>>(Obuf, woT, out, 4096, 2048, 2048);
}

// Round 4
// 246.710 us; speedup vs baseline: 1.4979x; 1.4979x over previous
//
#include <hip/hip_runtime.h>

typedef unsigned short u16;
typedef unsigned int u32;
typedef __bf16 bf16x4 __attribute__((ext_vector_type(4)));
typedef __bf16 bf16x8 __attribute__((ext_vector_type(8)));
typedef float f32x4 __attribute__((ext_vector_type(4)));
typedef u32 u32x4 __attribute__((ext_vector_type(4)));

struct __align__(4) U16x2 { u16 x, y; };
struct __align__(8) U16x4 { u16 x, y, z, w; };

#define DEV static __device__ __forceinline__

extern "C" __device__ float __ocml_exp2_f32(float);

DEV u16 f2bf(float f) {
  __bf16 h = (__bf16)f;
  return __builtin_bit_cast(u16, h);
}
DEV float bf2f(u16 u) { return __uint_as_float(((u32)u) << 16); }

DEV void gload16(const void* g, void* l) {
  __builtin_amdgcn_global_load_lds((const __attribute__((address_space(1))) char*)g,
                                   (__attribute__((address_space(3))) char*)l, 16, 0, 0);
}

DEV f32x4 mfma16(bf16x8 a, bf16x8 b, f32x4 c) {
  return __builtin_amdgcn_mfma_f32_16x16x32_bf16(a, b, c, 0, 0, 0);
}

// ---------------------------------------------------------------------------
// x fp32 -> bf16, 4 elems/thread
__global__ __launch_bounds__(256) void cvt_x(const float* __restrict__ x, u16* __restrict__ xb) {
  int i = blockIdx.x * 256 + threadIdx.x;
  float4 v = ((const float4*)x)[i];
  U16x4 o;
  o.x = f2bf(v.x); o.y = f2bf(v.y); o.z = f2bf(v.z); o.w = f2bf(v.w);
  ((U16x4*)xb)[i] = o;
}

// ---------------------------------------------------------------------------
// fp32 [R][C] -> bf16 dst[nOff + c][r] (transposed), ldd = R
__global__ __launch_bounds__(256) void tconv(const float* __restrict__ src, u16* __restrict__ dst,
                                             int C, int nOff, int ldd) {
  __shared__ float t[32][33];
  int bx = blockIdx.x, by = blockIdx.y;
  int tx = threadIdx.x, ty = threadIdx.y;
#pragma unroll
  for (int j = 0; j < 4; ++j)
    t[ty + 8 * j][tx] = src[(size_t)(by * 32 + ty + 8 * j) * C + bx * 32 + tx];
  __syncthreads();
#pragma unroll
  for (int j = 0; j < 4; ++j)
    dst[(size_t)(nOff + bx * 32 + ty + 8 * j) * ldd + by * 32 + tx] = f2bf(t[tx][ty + 8 * j]);
}

// ---------------------------------------------------------------------------
// bf16 qkv v-slice [b*2048+s][2560+kh*64+d] -> Vt[(b*8+kh)*64+d][s]
__global__ __launch_bounds__(256) void vtrans(const u16* __restrict__ qkv, u16* __restrict__ Vt) {
  __shared__ u16 t[32][33];
  int bx = blockIdx.x, by = blockIdx.y, bz = blockIdx.z;
  int tx = threadIdx.x, ty = threadIdx.y;
  int b = bz >> 3, kh = bz & 7;
  const u16* src = qkv + (size_t)(b * 2048 + bx * 32) * 3072 + 2560 + kh * 64 + by * 32;
#pragma unroll
  for (int j = 0; j < 4; ++j) t[ty + 8 * j][tx] = src[(size_t)(ty + 8 * j) * 3072 + tx];
  __syncthreads();
  u16* dst = Vt + ((size_t)bz * 64 + by * 32) * 2048 + bx * 32;
#pragma unroll
  for (int j = 0; j < 4; ++j) dst[(size_t)(ty + 8 * j) * 2048 + tx] = t[tx][ty + 8 * j];
}

// ---------------------------------------------------------------------------
// RoPE on q,k heads of qkv[4096][3072]; writes Q[b][h][s][64] (pre-scaled by
// 0.125*log2(e) so attn softmax runs in the exp2 domain), K[b][kh][s][64].
__global__ __launch_bounds__(256) void rope_qk(const u16* __restrict__ qkv,
                                               const float* __restrict__ fc,
                                               const float* __restrict__ fs,
                                               u16* __restrict__ Qo, u16* __restrict__ Ko) {
  int t = blockIdx.x * 256 + threadIdx.x;  // 5,242,880 total
  int d2 = t & 31;
  int rest = t >> 5;
  int h40 = rest % 40;
  int bs = rest / 40;  // b*2048 + s
  int s = bs & 2047;
  int b = bs >> 11;
  const u16* src;
  u16* dst;
  float qscale;
  if (h40 < 32) {
    src = qkv + (size_t)bs * 3072 + h40 * 64 + 2 * d2;
    dst = Qo + (((size_t)(b * 32 + h40) * 2048 + s) * 64 + 2 * d2);
    qscale = 0.18033688011112042f;  // 0.125 * log2(e)
  } else {
    int kh = h40 - 32;
    src = qkv + (size_t)bs * 3072 + 2048 + kh * 64 + 2 * d2;
    dst = Ko + (((size_t)(b * 8 + kh) * 2048 + s) * 64 + 2 * d2);
    qscale = 1.0f;
  }
  U16x2 v = *(const U16x2*)src;
  float xr = bf2f(v.x), xi = bf2f(v.y);
  float c = fc[s * 32 + d2] * qscale, sn = fs[s * 32 + d2] * qscale;
  U16x2 o;
  o.x = f2bf(xr * c - xi * sn);
  o.y = f2bf(xr * sn + xi * c);
  *(U16x2*)dst = o;
}

// ---------------------------------------------------------------------------
// C[M][N] = A[M][K] * BT[N][K]^T  (bf16 in, OutT out). 128x128 tile, BK=64,
// 4 waves (2x2), swizzled LDS, double-buffered global_load_lds staging.
template <typename OutT>
__global__ __launch_bounds__(256, 2) void gemm_bt(const u16* __restrict__ A,
                                                  const u16* __restrict__ BT,
                                                  OutT* __restrict__ C,
                                                  int M, int N, int K) {
  __shared__ __align__(16) char smem[65536];  // As[2]@0, Bs[2]@32768 (16384 each)
  const int tid = threadIdx.x;
  const int lane = tid & 63;
  const int wm = (tid >> 7) & 1, wn = (tid >> 6) & 1;
  const int tm = blockIdx.y, tn = blockIdx.x;
  const int Kb = K * 2;

  f32x4 acc[4][4];
#pragma unroll
  for (int i = 0; i < 4; ++i)
#pragma unroll
    for (int j = 0; j < 4; ++j) acc[i][j] = (f32x4){0.f, 0.f, 0.f, 0.f};

  const char* Ag = (const char*)A + (size_t)tm * 128 * Kb;
  const char* Bg = (const char*)BT + (size_t)tn * 128 * Kb;

  auto stage = [&](int buf, int t) {
#pragma unroll
    for (int i = 0; i < 4; ++i) {
      int vt = i * 256 + tid;
      int row = vt >> 3;
      int cb = (((vt & 7) << 4) ^ ((row & 7) << 4));
      gload16(Ag + (size_t)row * Kb + t * 128 + cb, smem + buf * 16384 + vt * 16);
      gload16(Bg + (size_t)row * Kb + t * 128 + cb, smem + 32768 + buf * 16384 + vt * 16);
    }
  };

  stage(0, 0);
  int cur = 0;
  const int NT = K >> 6;
  for (int t = 0; t < NT; ++t) {
    __syncthreads();
    if (t + 1 < NT) stage(cur ^ 1, t + 1);
    const char* As = smem + cur * 16384;
    const char* Bs = smem + 32768 + cur * 16384;
#pragma unroll
    for (int ks = 0; ks < 2; ++ks) {
      bf16x8 a[4], b[4];
#pragma unroll
      for (int mf = 0; mf < 4; ++mf) {
        int row = wm * 64 + mf * 16 + (lane & 15);
        int cb = (ks * 64 + ((lane >> 4) << 4)) ^ ((row & 7) << 4);
        a[mf] = *(const bf16x8*)(As + row * 128 + cb);
      }
#pragma unroll
      for (int nf = 0; nf < 4; ++nf) {
        int row = wn * 64 + nf * 16 + (lane & 15);
        int cb = (ks * 64 + ((lane >> 4) << 4)) ^ ((row & 7) << 4);
        b[nf] = *(const bf16x8*)(Bs + row * 128 + cb);
      }
#pragma unroll
      for (int mf = 0; mf < 4; ++mf)
#pragma unroll
        for (int nf = 0; nf < 4; ++nf) acc[mf][nf] = mfma16(a[mf], b[nf], acc[mf][nf]);
    }
    cur ^= 1;
  }
#pragma unroll
  for (int mf = 0; mf < 4; ++mf) {
    int row0 = tm * 128 + wm * 64 + mf * 16 + ((lane >> 4) << 2);
#pragma unroll
    for (int nf = 0; nf < 4; ++nf) {
      int col = tn * 128 + wn * 64 + nf * 16 + (lane & 15);
#pragma unroll
      for (int r = 0; r < 4; ++r) {
        float v = acc[mf][nf][r];
        if constexpr (sizeof(OutT) == 4)
          C[(size_t)(row0 + r) * N + col] = v;
        else
          C[(size_t)(row0 + r) * N + col] = f2bf(v);
      }
    }
  }
}

// ---------------------------------------------------------------------------
// Causal GQA flash attention, swapped-QK^T + in-register P (no P LDS tile).
// Block = (bx, h, b): processes q-tiles {bx, 15-bx} -> constant 34 K/V-tiles
// per block (perfect balance). Wave w owns q-rows [w*32, w*32+32) of the tile.
//
// Swapped QK^T: st = mfma(K_frag, Q_frag) = S^T tile. Lane l holds
// S[q = 16*mf2 + (l&15)][k = 16*nf + 4*(l>>4) + r]  -> row stats are 2-shuffle
// reductions; P->A-fragment is a closed-form 2-step xor-shuffle (verified:
// e.g. lane0,ks0,j4 <- lane16.P2[0][0].lo = P[0][4]; lane49,ks1,W[1].hi
// <- lane33.P2[3][1].hi = P[1][59]).
__global__ __launch_bounds__(256, 2) void attn(const u16* __restrict__ Q,
                                               const u16* __restrict__ Kt,
                                               const u16* __restrict__ Vt,
                                               u16* __restrict__ O) {
  __shared__ __align__(16) char smem[32768];  // K dbuf [0,16K), V dbuf [16K,32K)

  const int tid = threadIdx.x, lane = tid & 63, w = tid >> 6;
  const int q15 = lane & 15, g = lane >> 4;
  const int bx = blockIdx.x, h = blockIdx.y, b = blockIdx.z;
  const int kh = h >> 2;

  const char* Kg = (const char*)(Kt + ((size_t)(b * 8 + kh) * 2048 * 64));
  const char* Vg = (const char*)(Vt + ((size_t)(b * 8 + kh) * 64 * 2048));

  auto stageKV = [&](int buf, int kt) {
#pragma unroll
    for (int i = 0; i < 2; ++i) {
      int vt = i * 256 + tid;
      int row = vt >> 3;
      int cb = (((vt & 7) << 4) ^ ((row & 7) << 4));
      gload16(Kg + (size_t)(kt * 64 + row) * 128 + cb, smem + buf * 8192 + vt * 16);
      gload16(Vg + (size_t)row * 4096 + kt * 128 + cb, smem + 16384 + buf * 8192 + vt * 16);
    }
  };

#pragma unroll 1
  for (int ph = 0; ph < 2; ++ph) {
    const int qb = ph ? (15 - bx) : bx;
    const char* Qg = (const char*)(Q + (((size_t)(b * 32 + h) * 2048 + qb * 128) * 64));
    u16* Og = O + ((size_t)(b * 2048 + qb * 128) * 2048 + h * 64);

    // Q fragments (B-operand of swapped QK^T): rows = q, d-contiguous.
    bf16x8 qf[2][2];
#pragma unroll
    for (int mf2 = 0; mf2 < 2; ++mf2)
#pragma unroll
      for (int ks = 0; ks < 2; ++ks) {
        int row = w * 32 + mf2 * 16 + q15;
        qf[mf2][ks] = *(const bf16x8*)(Qg + row * 128 + ks * 64 + (g << 4));
      }

    f32x4 acc[2][4];
#pragma unroll
    for (int i = 0; i < 2; ++i)
#pragma unroll
      for (int j = 0; j < 4; ++j) acc[i][j] = (f32x4){0.f, 0.f, 0.f, 0.f};
    float m_r[2] = {-1e30f, -1e30f}, l_r[2] = {0.f, 0.f};

    __syncthreads();  // protect LDS dbuf across phases
    stageKV(0, 0);
    int cur = 0;
    const int nkt = 2 * qb + 2;
    for (int kt = 0; kt < nkt; ++kt) {
      __syncthreads();  // KV[cur] staged (compiler drains vmcnt before barrier)
      if (kt + 1 < nkt) stageKV(cur ^ 1, kt + 1);  // prefetch; drains next barrier
      const char* Ks = smem + cur * 8192;
      const char* Vs = smem + 16384 + cur * 8192;

      // swapped QK^T: st[mf2][nf] = S^T tile
      f32x4 st[2][4];
#pragma unroll
      for (int i = 0; i < 2; ++i)
#pragma unroll
        for (int j = 0; j < 4; ++j) st[i][j] = (f32x4){0.f, 0.f, 0.f, 0.f};
      __builtin_amdgcn_s_setprio(1);
#pragma unroll
      for (int ks = 0; ks < 2; ++ks) {
        bf16x8 kf[4];
#pragma unroll
        for (int nf = 0; nf < 4; ++nf) {
          int row = nf * 16 + q15;
          int cb = (ks * 64 + (g << 4)) ^ ((row & 7) << 4);
          kf[nf] = *(const bf16x8*)(Ks + row * 128 + cb);
        }
#pragma unroll
        for (int mf2 = 0; mf2 < 2; ++mf2)
#pragma unroll
          for (int nf = 0; nf < 4; ++nf)
            st[mf2][nf] = mfma16(kf[nf], qf[mf2][ks], st[mf2][nf]);
      }
      __builtin_amdgcn_s_setprio(0);

      // causal mask (diagonal tiles only): k = kt*64+nf*16+4g+r, q = ...+q15
      if (kt >= 2 * qb) {
#pragma unroll
        for (int mf2 = 0; mf2 < 2; ++mf2) {
          int qg = qb * 128 + w * 32 + mf2 * 16 + q15;
#pragma unroll
          for (int nf = 0; nf < 4; ++nf)
#pragma unroll
            for (int r = 0; r < 4; ++r) {
              int kg = kt * 64 + nf * 16 + 4 * g + r;
              if (kg > qg) st[mf2][nf][r] = -1e30f;
            }
        }
      }

      bf16x8 pa[2][2];
#pragma unroll
      for (int mf2 = 0; mf2 < 2; ++mf2) {
        // row max: 15 local fmax + 2 shuffles
        float vm = st[mf2][0][0];
#pragma unroll
        for (int nf = 0; nf < 4; ++nf)
#pragma unroll
          for (int r = 0; r < 4; ++r) vm = fmaxf(vm, st[mf2][nf][r]);
        vm = fmaxf(vm, __shfl_xor(vm, 16, 64));
        vm = fmaxf(vm, __shfl_xor(vm, 32, 64));
        float mn = fmaxf(m_r[mf2], vm);
        float cr = __ocml_exp2_f32(m_r[mf2] - mn);
        m_r[mf2] = mn;

        // P = exp2(S - mn), pack bf16 pairs; row sum of bf16-rounded values
        u32 P2[4][2];
        float vs = 0.f;
#pragma unroll
        for (int nf = 0; nf < 4; ++nf)
#pragma unroll
          for (int p = 0; p < 2; ++p) {
            float p0 = __ocml_exp2_f32(st[mf2][nf][2 * p] - mn);
            float p1 = __ocml_exp2_f32(st[mf2][nf][2 * p + 1] - mn);
            u16 b0 = f2bf(p0), b1 = f2bf(p1);
            vs += bf2f(b0) + bf2f(b1);
            P2[nf][p] = (u32)b0 | ((u32)b1 << 16);
          }
        vs += __shfl_xor(vs, 16, 64);
        vs += __shfl_xor(vs, 32, 64);
        l_r[mf2] = l_r[mf2] * cr + vs;

        // rescale acc (acc rows live at q' = 4g+r; cr lives at q = l&15)
        float cra[4];
#pragma unroll
        for (int r = 0; r < 4; ++r) cra[r] = __shfl(cr, 4 * g + r, 64);
#pragma unroll
        for (int nf = 0; nf < 4; ++nf)
#pragma unroll
          for (int r = 0; r < 4; ++r) acc[mf2][nf][r] *= cra[r];

        // P (C-layout) -> PA (A-fragment), 2-step xor-shuffle per ks
#pragma unroll
        for (int ks = 0; ks < 2; ++ks) {
          u32 A0 = P2[2 * ks][0], A1 = P2[2 * ks][1];
          u32 B0 = P2[2 * ks + 1][0], B1 = P2[2 * ks + 1][1];
          u32 An0 = __shfl_xor(A0, 16, 64), An1 = __shfl_xor(A1, 16, 64);
          u32 Bn0 = __shfl_xor(B0, 16, 64), Bn1 = __shfl_xor(B1, 16, 64);
          bool godd = (g & 1);
          u32 AG0 = godd ? An0 : A0, AG1 = godd ? An1 : A1;
          u32 AG2 = godd ? A0 : An0, AG3 = godd ? A1 : An1;
          u32 BG0 = godd ? Bn0 : B0, BG1 = godd ? Bn1 : B1;
          u32 BG2 = godd ? B0 : Bn0, BG3 = godd ? B1 : Bn1;
          bool ghi = (g & 2);
          u32 rc0 = __shfl_xor(ghi ? AG0 : BG0, 32, 64);
          u32 rc1 = __shfl_xor(ghi ? AG1 : BG1, 32, 64);
          u32 rc2 = __shfl_xor(ghi ? AG2 : BG2, 32, 64);
          u32 rc3 = __shfl_xor(ghi ? AG3 : BG3, 32, 64);
          u32x4 W;
          W.x = (g == 0) ? AG0 : (g == 3) ? BG0 : rc0;
          W.y = (g == 0) ? AG1 : (g == 3) ? BG1 : rc1;
          W.z = (g == 0) ? AG2 : (g == 3) ? BG2 : rc2;
          W.w = (g == 0) ? AG3 : (g == 3) ? BG3 : rc3;
          pa[mf2][ks] = __builtin_bit_cast(bf16x8, W);
        }
      }

      // PV: O[q' = mf2*16+4g+r][d = nf*16+q15] += PA . V^T
#pragma unroll
      for (int ks = 0; ks < 2; ++ks) {
        bf16x8 vb[4];
#pragma unroll
        for (int nf = 0; nf < 4; ++nf) {
          int vrow = nf * 16 + q15;
          int cb = (ks * 64 + (g << 4)) ^ ((vrow & 7) << 4);
          vb[nf] = *(const bf16x8*)(Vs + vrow * 128 + cb);
        }
        __builtin_amdgcn_s_setprio(1);
#pragma unroll
        for (int mf2 = 0; mf2 < 2; ++mf2)
#pragma unroll
          for (int nf = 0; nf < 4; ++nf)
            acc[mf2][nf] = mfma16(pa[mf2][ks], vb[nf], acc[mf2][nf]);
        __builtin_amdgcn_s_setprio(0);
      }
      cur ^= 1;
    }

    // epilogue: normalize by l (lives at q = l&15; acc rows at q' = 4g+r)
#pragma unroll
    for (int mf2 = 0; mf2 < 2; ++mf2) {
      float la[4];
#pragma unroll
      for (int r = 0; r < 4; ++r) la[r] = __shfl(l_r[mf2], 4 * g + r, 64);
#pragma unroll
      for (int r = 0; r < 4; ++r) {
        int row = w * 32 + mf2 * 16 + 4 * g + r;
        float li = 1.f / la[r];
#pragma unroll
        for (int nf = 0; nf < 4; ++nf)
          Og[(size_t)row * 2048 + nf * 16 + q15] = f2bf(acc[mf2][nf][r] * li);
      }
    }
  }
}

// ---------------------------------------------------------------------------
extern "C" void kernel_launch(void* const* d_in, const int* in_sizes, int n_in,
                              void* d_out, int out_size, void* d_ws, size_t ws_size,
                              hipStream_t stream) {
  const float* x = (const float*)d_in[0];
  const float* fc = (const float*)d_in[1];
  const float* fs = (const float*)d_in[2];
  const float* wq = (const float*)d_in[3];
  const float* wk = (const float*)d_in[4];
  const float* wv = (const float*)d_in[5];
  const float* wo = (const float*)d_in[6];
  float* out = (float*)d_out;
  char* ws = (char*)d_ws;

  // Compact workspace layout (60 MB total):
  u16* xb    = (u16*)(ws);                 // [4096][2048] 16 MB  (reused as Q)
  u16* qkv   = (u16*)(ws + 16777216);      // [4096][3072] 24 MB  (reused as O)
  u16* woT   = (u16*)(ws + 41943040);      // [2048][2048]  8 MB
  u16* wqkvT = (u16*)(ws + 50331648);      // [3072][2048] 12 MB (dead after QKV GEMM)
  u16* Kbuf  = (u16*)(ws + 50331648);      // [2][8][2048][64] 4 MB (overlays wqkvT)
  u16* Vtb   = (u16*)(ws + 54525952);      // [2][8][64][2048] 4 MB (overlays wqkvT)
  u16* Qbuf = xb;
  u16* Obuf = qkv;

  dim3 tb(32, 8);
  cvt_x<<<dim3(8192), dim3(256), 0, stream>>>(x, xb);
  tconv<<<dim3(64, 64), tb, 0, stream>>>(wq, wqkvT, 2048, 0, 2048);
  tconv<<<dim3(16, 64), tb, 0, stream>>>(wk, wqkvT, 512, 2048, 2048);
  tconv<<<dim3(16, 64), tb, 0, stream>>>(wv, wqkvT, 512, 2560, 2048);
  tconv<<<dim3(64, 64), tb, 0, stream>>>(wo, woT, 2048, 0, 2048);
  gemm_bt<u16><<<dim3(24, 32), dim3(256), 0, stream>>>(xb, wqkvT, qkv, 4096, 3072, 2048);
  rope_qk<<<dim3(20480), dim3(256), 0, stream>>>(qkv, fc, fs, Qbuf, Kbuf);
  vtrans<<<dim3(64, 2, 16), tb, 0, stream>>>(qkv, Vtb);
  attn<<<dim3(8, 32, 2), dim3(256), 0, stream>>>(Qbuf, Kbuf, Vtb, Obuf);
  gemm_bt<float><<<dim3(16, 32), dim3(256), 0, stream>>>(Obuf, woT, out, 4096, 2048, 2048);
}

// Round 5
// 243.584 us; speedup vs baseline: 1.5172x; 1.0128x over previous
//
#include <hip/hip_runtime.h>

typedef unsigned short u16;
typedef unsigned int u32;
typedef __bf16 bf16x4 __attribute__((ext_vector_type(4)));
typedef __bf16 bf16x8 __attribute__((ext_vector_type(8)));
typedef float f32x4 __attribute__((ext_vector_type(4)));
typedef u32 u32x4 __attribute__((ext_vector_type(4)));

struct __align__(4) U16x2 { u16 x, y; };
struct __align__(8) U16x4 { u16 x, y, z, w; };

#define DEV static __device__ __forceinline__

extern "C" __device__ float __ocml_exp2_f32(float);

DEV u16 f2bf(float f) {
  __bf16 h = (__bf16)f;
  return __builtin_bit_cast(u16, h);
}
DEV float bf2f(u16 u) { return __uint_as_float(((u32)u) << 16); }

DEV void gload16(const void* g, void* l) {
  __builtin_amdgcn_global_load_lds((const __attribute__((address_space(1))) char*)g,
                                   (__attribute__((address_space(3))) char*)l, 16, 0, 0);
}

DEV f32x4 mfma16(bf16x8 a, bf16x8 b, f32x4 c) {
  return __builtin_amdgcn_mfma_f32_16x16x32_bf16(a, b, c, 0, 0, 0);
}

// ---------------------------------------------------------------------------
// x fp32 -> bf16, 4 elems/thread
__global__ __launch_bounds__(256) void cvt_x(const float* __restrict__ x, u16* __restrict__ xb) {
  int i = blockIdx.x * 256 + threadIdx.x;
  float4 v = ((const float4*)x)[i];
  U16x4 o;
  o.x = f2bf(v.x); o.y = f2bf(v.y); o.z = f2bf(v.z); o.w = f2bf(v.w);
  ((U16x4*)xb)[i] = o;
}

// ---------------------------------------------------------------------------
// fp32 [R][C] -> bf16 dst[nOff + c][r] (transposed), ldd = R
__global__ __launch_bounds__(256) void tconv(const float* __restrict__ src, u16* __restrict__ dst,
                                             int C, int nOff, int ldd) {
  __shared__ float t[32][33];
  int bx = blockIdx.x, by = blockIdx.y;
  int tx = threadIdx.x, ty = threadIdx.y;
#pragma unroll
  for (int j = 0; j < 4; ++j)
    t[ty + 8 * j][tx] = src[(size_t)(by * 32 + ty + 8 * j) * C + bx * 32 + tx];
  __syncthreads();
#pragma unroll
  for (int j = 0; j < 4; ++j)
    dst[(size_t)(nOff + bx * 32 + ty + 8 * j) * ldd + by * 32 + tx] = f2bf(t[tx][ty + 8 * j]);
}

// ---------------------------------------------------------------------------
// bf16 qkv v-slice [b*2048+s][2560+kh*64+d] -> Vt[(b*8+kh)*64+d][s]
__global__ __launch_bounds__(256) void vtrans(const u16* __restrict__ qkv, u16* __restrict__ Vt) {
  __shared__ u16 t[32][33];
  int bx = blockIdx.x, by = blockIdx.y, bz = blockIdx.z;
  int tx = threadIdx.x, ty = threadIdx.y;
  int b = bz >> 3, kh = bz & 7;
  const u16* src = qkv + (size_t)(b * 2048 + bx * 32) * 3072 + 2560 + kh * 64 + by * 32;
#pragma unroll
  for (int j = 0; j < 4; ++j) t[ty + 8 * j][tx] = src[(size_t)(ty + 8 * j) * 3072 + tx];
  __syncthreads();
  u16* dst = Vt + ((size_t)bz * 64 + by * 32) * 2048 + bx * 32;
#pragma unroll
  for (int j = 0; j < 4; ++j) dst[(size_t)(ty + 8 * j) * 2048 + tx] = t[tx][ty + 8 * j];
}

// ---------------------------------------------------------------------------
// RoPE on q,k heads of qkv[4096][3072]; writes Q[b][h][s][64] (pre-scaled by
// 0.125*log2(e) so attn softmax runs in the exp2 domain), K[b][kh][s][64].
__global__ __launch_bounds__(256) void rope_qk(const u16* __restrict__ qkv,
                                               const float* __restrict__ fc,
                                               const float* __restrict__ fs,
                                               u16* __restrict__ Qo, u16* __restrict__ Ko) {
  int t = blockIdx.x * 256 + threadIdx.x;  // 5,242,880 total
  int d2 = t & 31;
  int rest = t >> 5;
  int h40 = rest % 40;
  int bs = rest / 40;  // b*2048 + s
  int s = bs & 2047;
  int b = bs >> 11;
  const u16* src;
  u16* dst;
  float qscale;
  if (h40 < 32) {
    src = qkv + (size_t)bs * 3072 + h40 * 64 + 2 * d2;
    dst = Qo + (((size_t)(b * 32 + h40) * 2048 + s) * 64 + 2 * d2);
    qscale = 0.18033688011112042f;  // 0.125 * log2(e)
  } else {
    int kh = h40 - 32;
    src = qkv + (size_t)bs * 3072 + 2048 + kh * 64 + 2 * d2;
    dst = Ko + (((size_t)(b * 8 + kh) * 2048 + s) * 64 + 2 * d2);
    qscale = 1.0f;
  }
  U16x2 v = *(const U16x2*)src;
  float xr = bf2f(v.x), xi = bf2f(v.y);
  float c = fc[s * 32 + d2] * qscale, sn = fs[s * 32 + d2] * qscale;
  U16x2 o;
  o.x = f2bf(xr * c - xi * sn);
  o.y = f2bf(xr * sn + xi * c);
  *(U16x2*)dst = o;
}

// ---------------------------------------------------------------------------
// C[M][N] = A[M][K] * BT[N][K]^T  (bf16 in, OutT out). 128x128 tile, BK=64,
// 4 waves (2x2), swizzled LDS, double-buffered global_load_lds staging.
template <typename OutT>
__global__ __launch_bounds__(256, 2) void gemm_bt(const u16* __restrict__ A,
                                                  const u16* __restrict__ BT,
                                                  OutT* __restrict__ C,
                                                  int M, int N, int K) {
  __shared__ __align__(16) char smem[65536];  // As[2]@0, Bs[2]@32768 (16384 each)
  const int tid = threadIdx.x;
  const int lane = tid & 63;
  const int wm = (tid >> 7) & 1, wn = (tid >> 6) & 1;
  const int tm = blockIdx.y, tn = blockIdx.x;
  const int Kb = K * 2;

  f32x4 acc[4][4];
#pragma unroll
  for (int i = 0; i < 4; ++i)
#pragma unroll
    for (int j = 0; j < 4; ++j) acc[i][j] = (f32x4){0.f, 0.f, 0.f, 0.f};

  const char* Ag = (const char*)A + (size_t)tm * 128 * Kb;
  const char* Bg = (const char*)BT + (size_t)tn * 128 * Kb;

  auto stage = [&](int buf, int t) {
#pragma unroll
    for (int i = 0; i < 4; ++i) {
      int vt = i * 256 + tid;
      int row = vt >> 3;
      int cb = (((vt & 7) << 4) ^ ((row & 7) << 4));
      gload16(Ag + (size_t)row * Kb + t * 128 + cb, smem + buf * 16384 + vt * 16);
      gload16(Bg + (size_t)row * Kb + t * 128 + cb, smem + 32768 + buf * 16384 + vt * 16);
    }
  };

  stage(0, 0);
  int cur = 0;
  const int NT = K >> 6;
  for (int t = 0; t < NT; ++t) {
    __syncthreads();
    if (t + 1 < NT) stage(cur ^ 1, t + 1);
    const char* As = smem + cur * 16384;
    const char* Bs = smem + 32768 + cur * 16384;
#pragma unroll
    for (int ks = 0; ks < 2; ++ks) {
      bf16x8 a[4], b[4];
#pragma unroll
      for (int mf = 0; mf < 4; ++mf) {
        int row = wm * 64 + mf * 16 + (lane & 15);
        int cb = (ks * 64 + ((lane >> 4) << 4)) ^ ((row & 7) << 4);
        a[mf] = *(const bf16x8*)(As + row * 128 + cb);
      }
#pragma unroll
      for (int nf = 0; nf < 4; ++nf) {
        int row = wn * 64 + nf * 16 + (lane & 15);
        int cb = (ks * 64 + ((lane >> 4) << 4)) ^ ((row & 7) << 4);
        b[nf] = *(const bf16x8*)(Bs + row * 128 + cb);
      }
#pragma unroll
      for (int mf = 0; mf < 4; ++mf)
#pragma unroll
        for (int nf = 0; nf < 4; ++nf) acc[mf][nf] = mfma16(a[mf], b[nf], acc[mf][nf]);
    }
    cur ^= 1;
  }
#pragma unroll
  for (int mf = 0; mf < 4; ++mf) {
    int row0 = tm * 128 + wm * 64 + mf * 16 + ((lane >> 4) << 2);
#pragma unroll
    for (int nf = 0; nf < 4; ++nf) {
      int col = tn * 128 + wn * 64 + nf * 16 + (lane & 15);
#pragma unroll
      for (int r = 0; r < 4; ++r) {
        float v = acc[mf][nf][r];
        if constexpr (sizeof(OutT) == 4)
          C[(size_t)(row0 + r) * N + col] = v;
        else
          C[(size_t)(row0 + r) * N + col] = f2bf(v);
      }
    }
  }
}

// ---------------------------------------------------------------------------
// Causal GQA flash attention, swapped-QK^T + in-register P.
// Block = (bx, h, b), 128 threads (2 waves), QBLK=64: processes q-tiles
// {bx, 31-bx} -> constant 33 K/V-tiles per block; grid 1024 = 4 blocks/CU.
// Wave w owns q-rows [w*32, w*32+32) of the tile (same per-wave layout as R4).
// VALU diet: f32 row-sums; T13 defer-rescale (THR=8 in exp2 domain).
__global__ __launch_bounds__(128, 2) void attn(const u16* __restrict__ Q,
                                               const u16* __restrict__ Kt,
                                               const u16* __restrict__ Vt,
                                               u16* __restrict__ O) {
  __shared__ __align__(16) char smem[32768];  // K dbuf [0,16K), V dbuf [16K,32K)

  const int tid = threadIdx.x, lane = tid & 63, w = tid >> 6;  // w in {0,1}
  const int q15 = lane & 15, g = lane >> 4;
  const int bx = blockIdx.x, h = blockIdx.y, b = blockIdx.z;
  const int kh = h >> 2;

  const char* Kg = (const char*)(Kt + ((size_t)(b * 8 + kh) * 2048 * 64));
  const char* Vg = (const char*)(Vt + ((size_t)(b * 8 + kh) * 64 * 2048));

  auto stageKV = [&](int buf, int kt) {
#pragma unroll
    for (int i = 0; i < 4; ++i) {
      int vt = i * 128 + tid;  // 0..511
      int row = vt >> 3;
      int cb = (((vt & 7) << 4) ^ ((row & 7) << 4));
      gload16(Kg + (size_t)(kt * 64 + row) * 128 + cb, smem + buf * 8192 + vt * 16);
      gload16(Vg + (size_t)row * 4096 + kt * 128 + cb, smem + 16384 + buf * 8192 + vt * 16);
    }
  };

#pragma unroll 1
  for (int ph = 0; ph < 2; ++ph) {
    const int qb = ph ? (31 - bx) : bx;  // q-tile of 64 rows
    const char* Qg = (const char*)(Q + (((size_t)(b * 32 + h) * 2048 + qb * 64) * 64));
    u16* Og = O + ((size_t)(b * 2048 + qb * 64) * 2048 + h * 64);

    // Q fragments (B-operand of swapped QK^T): rows = q, d-contiguous.
    bf16x8 qf[2][2];
#pragma unroll
    for (int mf2 = 0; mf2 < 2; ++mf2)
#pragma unroll
      for (int ks = 0; ks < 2; ++ks) {
        int row = w * 32 + mf2 * 16 + q15;
        qf[mf2][ks] = *(const bf16x8*)(Qg + row * 128 + ks * 64 + (g << 4));
      }

    f32x4 acc[2][4];
#pragma unroll
    for (int i = 0; i < 2; ++i)
#pragma unroll
      for (int j = 0; j < 4; ++j) acc[i][j] = (f32x4){0.f, 0.f, 0.f, 0.f};
    float m_r[2] = {-1e30f, -1e30f}, l_r[2] = {0.f, 0.f};

    __syncthreads();  // protect LDS dbuf across phases
    stageKV(0, 0);
    int cur = 0;
    const int nkt = qb + 1;
    for (int kt = 0; kt < nkt; ++kt) {
      __syncthreads();  // KV[cur] staged (compiler drains vmcnt before barrier)
      if (kt + 1 < nkt) stageKV(cur ^ 1, kt + 1);  // prefetch; drains next barrier
      const char* Ks = smem + cur * 8192;
      const char* Vs = smem + 16384 + cur * 8192;

      // swapped QK^T: st[mf2][nf] = S^T tile; lane holds
      // S[q = 16*mf2 + q15][k = 16*nf + 4*g + r]
      f32x4 st[2][4];
#pragma unroll
      for (int i = 0; i < 2; ++i)
#pragma unroll
        for (int j = 0; j < 4; ++j) st[i][j] = (f32x4){0.f, 0.f, 0.f, 0.f};
      __builtin_amdgcn_s_setprio(1);
#pragma unroll
      for (int ks = 0; ks < 2; ++ks) {
        bf16x8 kf[4];
#pragma unroll
        for (int nf = 0; nf < 4; ++nf) {
          int row = nf * 16 + q15;
          int cb = (ks * 64 + (g << 4)) ^ ((row & 7) << 4);
          kf[nf] = *(const bf16x8*)(Ks + row * 128 + cb);
        }
#pragma unroll
        for (int mf2 = 0; mf2 < 2; ++mf2)
#pragma unroll
          for (int nf = 0; nf < 4; ++nf)
            st[mf2][nf] = mfma16(kf[nf], qf[mf2][ks], st[mf2][nf]);
      }
      __builtin_amdgcn_s_setprio(0);

      // causal mask (diagonal tile only): k = kt*64+nf*16+4g+r, q = qb*64+...
      if (kt >= qb) {
#pragma unroll
        for (int mf2 = 0; mf2 < 2; ++mf2) {
          int qg = qb * 64 + w * 32 + mf2 * 16 + q15;
#pragma unroll
          for (int nf = 0; nf < 4; ++nf)
#pragma unroll
            for (int r = 0; r < 4; ++r) {
              int kg = kt * 64 + nf * 16 + 4 * g + r;
              if (kg > qg) st[mf2][nf][r] = -1e30f;
            }
        }
      }

      bf16x8 pa[2][2];
#pragma unroll
      for (int mf2 = 0; mf2 < 2; ++mf2) {
        // row max: 15 local fmax + 2 shuffles (for the defer check)
        float vm = st[mf2][0][0];
#pragma unroll
        for (int nf = 0; nf < 4; ++nf)
#pragma unroll
          for (int r = 0; r < 4; ++r) vm = fmaxf(vm, st[mf2][nf][r]);
        vm = fmaxf(vm, __shfl_xor(vm, 16, 64));
        vm = fmaxf(vm, __shfl_xor(vm, 32, 64));

        // T13 defer-rescale: only rescale when max grew by > 8 (exp2 domain;
        // P bounded by 2^8, f32 l/acc have headroom, O/l ratio exact).
        const bool rescale = !__all(vm - m_r[mf2] <= 8.0f);
        float cr = 1.0f;
        if (rescale) {
          float mn = fmaxf(m_r[mf2], vm);
          cr = __ocml_exp2_f32(m_r[mf2] - mn);
          m_r[mf2] = mn;
        }

        // P = exp2(S - m), pack bf16 pairs; f32 row sum (pre-rounding)
        u32 P2[4][2];
        float vs = 0.f;
        const float mn = m_r[mf2];
#pragma unroll
        for (int nf = 0; nf < 4; ++nf)
#pragma unroll
          for (int p = 0; p < 2; ++p) {
            float p0 = __ocml_exp2_f32(st[mf2][nf][2 * p] - mn);
            float p1 = __ocml_exp2_f32(st[mf2][nf][2 * p + 1] - mn);
            vs += p0 + p1;
            P2[nf][p] = (u32)f2bf(p0) | ((u32)f2bf(p1) << 16);
          }
        vs += __shfl_xor(vs, 16, 64);
        vs += __shfl_xor(vs, 32, 64);

        if (rescale) {
          l_r[mf2] = l_r[mf2] * cr + vs;
          // acc rows live at q' = 4g+r; cr lives at q = l&15
          float cra[4];
#pragma unroll
          for (int r = 0; r < 4; ++r) cra[r] = __shfl(cr, 4 * g + r, 64);
#pragma unroll
          for (int nf = 0; nf < 4; ++nf)
#pragma unroll
            for (int r = 0; r < 4; ++r) acc[mf2][nf][r] *= cra[r];
        } else {
          l_r[mf2] += vs;
        }

        // P (C-layout) -> PA (A-fragment), 2-step xor-shuffle per ks
#pragma unroll
        for (int ks = 0; ks < 2; ++ks) {
          u32 A0 = P2[2 * ks][0], A1 = P2[2 * ks][1];
          u32 B0 = P2[2 * ks + 1][0], B1 = P2[2 * ks + 1][1];
          u32 An0 = __shfl_xor(A0, 16, 64), An1 = __shfl_xor(A1, 16, 64);
          u32 Bn0 = __shfl_xor(B0, 16, 64), Bn1 = __shfl_xor(B1, 16, 64);
          bool godd = (g & 1);
          u32 AG0 = godd ? An0 : A0, AG1 = godd ? An1 : A1;
          u32 AG2 = godd ? A0 : An0, AG3 = godd ? A1 : An1;
          u32 BG0 = godd ? Bn0 : B0, BG1 = godd ? Bn1 : B1;
          u32 BG2 = godd ? B0 : Bn0, BG3 = godd ? B1 : Bn1;
          bool ghi = (g & 2);
          u32 rc0 = __shfl_xor(ghi ? AG0 : BG0, 32, 64);
          u32 rc1 = __shfl_xor(ghi ? AG1 : BG1, 32, 64);
          u32 rc2 = __shfl_xor(ghi ? AG2 : BG2, 32, 64);
          u32 rc3 = __shfl_xor(ghi ? AG3 : BG3, 32, 64);
          u32x4 W;
          W.x = (g == 0) ? AG0 : (g == 3) ? BG0 : rc0;
          W.y = (g == 0) ? AG1 : (g == 3) ? BG1 : rc1;
          W.z = (g == 0) ? AG2 : (g == 3) ? BG2 : rc2;
          W.w = (g == 0) ? AG3 : (g == 3) ? BG3 : rc3;
          pa[mf2][ks] = __builtin_bit_cast(bf16x8, W);
        }
      }

      // PV: O[q' = mf2*16+4g+r][d = nf*16+q15] += PA . V^T
#pragma unroll
      for (int ks = 0; ks < 2; ++ks) {
        bf16x8 vb[4];
#pragma unroll
        for (int nf = 0; nf < 4; ++nf) {
          int vrow = nf * 16 + q15;
          int cb = (ks * 64 + (g << 4)) ^ ((vrow & 7) << 4);
          vb[nf] = *(const bf16x8*)(Vs + vrow * 128 + cb);
        }
        __builtin_amdgcn_s_setprio(1);
#pragma unroll
        for (int mf2 = 0; mf2 < 2; ++mf2)
#pragma unroll
          for (int nf = 0; nf < 4; ++nf)
            acc[mf2][nf] = mfma16(pa[mf2][ks], vb[nf], acc[mf2][nf]);
        __builtin_amdgcn_s_setprio(0);
      }
      cur ^= 1;
    }

    // epilogue: normalize by l (lives at q = l&15; acc rows at q' = 4g+r)
#pragma unroll
    for (int mf2 = 0; mf2 < 2; ++mf2) {
      float la[4];
#pragma unroll
      for (int r = 0; r < 4; ++r) la[r] = __shfl(l_r[mf2], 4 * g + r, 64);
#pragma unroll
      for (int r = 0; r < 4; ++r) {
        int row = w * 32 + mf2 * 16 + 4 * g + r;
        float li = 1.f / la[r];
#pragma unroll
        for (int nf = 0; nf < 4; ++nf)
          Og[(size_t)row * 2048 + nf * 16 + q15] = f2bf(acc[mf2][nf][r] * li);
      }
    }
  }
}

// ---------------------------------------------------------------------------
extern "C" void kernel_launch(void* const* d_in, const int* in_sizes, int n_in,
                              void* d_out, int out_size, void* d_ws, size_t ws_size,
                              hipStream_t stream) {
  const float* x = (const float*)d_in[0];
  const float* fc = (const float*)d_in[1];
  const float* fs = (const float*)d_in[2];
  const float* wq = (const float*)d_in[3];
  const float* wk = (const float*)d_in[4];
  const float* wv = (const float*)d_in[5];
  const float* wo = (const float*)d_in[6];
  float* out = (float*)d_out;
  char* ws = (char*)d_ws;

  // Compact workspace layout (60 MB total):
  u16* xb    = (u16*)(ws);                 // [4096][2048] 16 MB  (reused as Q)
  u16* qkv   = (u16*)(ws + 16777216);      // [4096][3072] 24 MB  (reused as O)
  u16* woT   = (u16*)(ws + 41943040);      // [2048][2048]  8 MB
  u16* wqkvT = (u16*)(ws + 50331648);      // [3072][2048] 12 MB (dead after QKV GEMM)
  u16* Kbuf  = (u16*)(ws + 50331648);      // [2][8][2048][64] 4 MB (overlays wqkvT)
  u16* Vtb   = (u16*)(ws + 54525952);      // [2][8][64][2048] 4 MB (overlays wqkvT)
  u16* Qbuf = xb;
  u16* Obuf = qkv;

  dim3 tb(32, 8);
  cvt_x<<<dim3(8192), dim3(256), 0, stream>>>(x, xb);
  tconv<<<dim3(64, 64), tb, 0, stream>>>(wq, wqkvT, 2048, 0, 2048);
  tconv<<<dim3(16, 64), tb, 0, stream>>>(wk, wqkvT, 512, 2048, 2048);
  tconv<<<dim3(16, 64), tb, 0, stream>>>(wv, wqkvT, 512, 2560, 2048);
  tconv<<<dim3(64, 64), tb, 0, stream>>>(wo, woT, 2048, 0, 2048);
  gemm_bt<u16><<<dim3(24, 32), dim3(256), 0, stream>>>(xb, wqkvT, qkv, 4096, 3072, 2048);
  rope_qk<<<dim3(20480), dim3(256), 0, stream>>>(qkv, fc, fs, Qbuf, Kbuf);
  vtrans<<<dim3(64, 2, 16), tb, 0, stream>>>(qkv, Vtb);
  attn<<<dim3(16, 32, 2), dim3(128), 0, stream>>>(Qbuf, Kbuf, Vtb, Obuf);
  gemm_bt<float><<<dim3(16, 32), dim3(256), 0, stream>>>(Obuf, woT, out, 4096, 2048, 2048);
}

// Round 6
// 230.804 us; speedup vs baseline: 1.6012x; 1.0554x over previous
//
#include <hip/hip_runtime.h>

typedef unsigned short u16;
typedef unsigned int u32;
typedef __bf16 bf16x4 __attribute__((ext_vector_type(4)));
typedef __bf16 bf16x8 __attribute__((ext_vector_type(8)));
typedef float f32x4 __attribute__((ext_vector_type(4)));
typedef u32 u32x2 __attribute__((ext_vector_type(2)));
typedef short s16x4 __attribute__((ext_vector_type(4)));

struct __align__(4) U16x2 { u16 x, y; };
struct __align__(8) U16x4 { u16 x, y, z, w; };

#define DEV static __device__ __forceinline__

extern "C" __device__ float __ocml_exp2_f32(float);

DEV u16 f2bf(float f) {
  __bf16 h = (__bf16)f;
  return __builtin_bit_cast(u16, h);
}
DEV float bf2f(u16 u) { return __uint_as_float(((u32)u) << 16); }

DEV void gload16(const void* g, void* l) {
  __builtin_amdgcn_global_load_lds((const __attribute__((address_space(1))) char*)g,
                                   (__attribute__((address_space(3))) char*)l, 16, 0, 0);
}

DEV f32x4 mfma16(bf16x8 a, bf16x8 b, f32x4 c) {
  return __builtin_amdgcn_mfma_f32_16x16x32_bf16(a, b, c, 0, 0, 0);
}

// K=16 MFMA: A/B are 4 bf16 (2 VGPRs). A-frag: lane holds row=lane&15,
// k = 4*(lane>>4)+j  -- matches the C-layout of a previous MFMA exactly.
DEV f32x4 mfma_k16(s16x4 a, s16x4 b, f32x4 c) {
#if __has_builtin(__builtin_amdgcn_mfma_f32_16x16x16bf16_1k)
  return __builtin_amdgcn_mfma_f32_16x16x16bf16_1k(a, b, c, 0, 0, 0);
#else
  f32x4 d;
  asm("v_mfma_f32_16x16x16_bf16 %0, %1, %2, %3"
      : "=v"(d)
      : "v"(a), "v"(b), "0"(c));
  return d;
#endif
}

// ---------------------------------------------------------------------------
// x fp32 -> bf16, 4 elems/thread
__global__ __launch_bounds__(256) void cvt_x(const float* __restrict__ x, u16* __restrict__ xb) {
  int i = blockIdx.x * 256 + threadIdx.x;
  float4 v = ((const float4*)x)[i];
  U16x4 o;
  o.x = f2bf(v.x); o.y = f2bf(v.y); o.z = f2bf(v.z); o.w = f2bf(v.w);
  ((U16x4*)xb)[i] = o;
}

// ---------------------------------------------------------------------------
// fp32 [R][C] -> bf16 dst[nOff + c][r] (transposed), ldd = R
__global__ __launch_bounds__(256) void tconv(const float* __restrict__ src, u16* __restrict__ dst,
                                             int C, int nOff, int ldd) {
  __shared__ float t[32][33];
  int bx = blockIdx.x, by = blockIdx.y;
  int tx = threadIdx.x, ty = threadIdx.y;
#pragma unroll
  for (int j = 0; j < 4; ++j)
    t[ty + 8 * j][tx] = src[(size_t)(by * 32 + ty + 8 * j) * C + bx * 32 + tx];
  __syncthreads();
#pragma unroll
  for (int j = 0; j < 4; ++j)
    dst[(size_t)(nOff + bx * 32 + ty + 8 * j) * ldd + by * 32 + tx] = f2bf(t[tx][ty + 8 * j]);
}

// ---------------------------------------------------------------------------
// bf16 qkv v-slice [b*2048+s][2560+kh*64+d] -> Vt[(b*8+kh)*64+d][s]
__global__ __launch_bounds__(256) void vtrans(const u16* __restrict__ qkv, u16* __restrict__ Vt) {
  __shared__ u16 t[32][33];
  int bx = blockIdx.x, by = blockIdx.y, bz = blockIdx.z;
  int tx = threadIdx.x, ty = threadIdx.y;
  int b = bz >> 3, kh = bz & 7;
  const u16* src = qkv + (size_t)(b * 2048 + bx * 32) * 3072 + 2560 + kh * 64 + by * 32;
#pragma unroll
  for (int j = 0; j < 4; ++j) t[ty + 8 * j][tx] = src[(size_t)(ty + 8 * j) * 3072 + tx];
  __syncthreads();
  u16* dst = Vt + ((size_t)bz * 64 + by * 32) * 2048 + bx * 32;
#pragma unroll
  for (int j = 0; j < 4; ++j) dst[(size_t)(ty + 8 * j) * 2048 + tx] = t[tx][ty + 8 * j];
}

// ---------------------------------------------------------------------------
// RoPE on q,k heads of qkv[4096][3072]; writes Q[b][h][s][64] (pre-scaled by
// 0.125*log2(e) so attn softmax runs in the exp2 domain), K[b][kh][s][64].
__global__ __launch_bounds__(256) void rope_qk(const u16* __restrict__ qkv,
                                               const float* __restrict__ fc,
                                               const float* __restrict__ fs,
                                               u16* __restrict__ Qo, u16* __restrict__ Ko) {
  int t = blockIdx.x * 256 + threadIdx.x;  // 5,242,880 total
  int d2 = t & 31;
  int rest = t >> 5;
  int h40 = rest % 40;
  int bs = rest / 40;  // b*2048 + s
  int s = bs & 2047;
  int b = bs >> 11;
  const u16* src;
  u16* dst;
  float qscale;
  if (h40 < 32) {
    src = qkv + (size_t)bs * 3072 + h40 * 64 + 2 * d2;
    dst = Qo + (((size_t)(b * 32 + h40) * 2048 + s) * 64 + 2 * d2);
    qscale = 0.18033688011112042f;  // 0.125 * log2(e)
  } else {
    int kh = h40 - 32;
    src = qkv + (size_t)bs * 3072 + 2048 + kh * 64 + 2 * d2;
    dst = Ko + (((size_t)(b * 8 + kh) * 2048 + s) * 64 + 2 * d2);
    qscale = 1.0f;
  }
  U16x2 v = *(const U16x2*)src;
  float xr = bf2f(v.x), xi = bf2f(v.y);
  float c = fc[s * 32 + d2] * qscale, sn = fs[s * 32 + d2] * qscale;
  U16x2 o;
  o.x = f2bf(xr * c - xi * sn);
  o.y = f2bf(xr * sn + xi * c);
  *(U16x2*)dst = o;
}

// ---------------------------------------------------------------------------
// C[M][N] = A[M][K] * BT[N][K]^T  (bf16 in, OutT out). 128x128 tile, BK=64,
// 4 waves (2x2), swizzled LDS, double-buffered global_load_lds staging.
template <typename OutT>
__global__ __launch_bounds__(256, 2) void gemm_bt(const u16* __restrict__ A,
                                                  const u16* __restrict__ BT,
                                                  OutT* __restrict__ C,
                                                  int M, int N, int K) {
  __shared__ __align__(16) char smem[65536];  // As[2]@0, Bs[2]@32768 (16384 each)
  const int tid = threadIdx.x;
  const int lane = tid & 63;
  const int wm = (tid >> 7) & 1, wn = (tid >> 6) & 1;
  const int tm = blockIdx.y, tn = blockIdx.x;
  const int Kb = K * 2;

  f32x4 acc[4][4];
#pragma unroll
  for (int i = 0; i < 4; ++i)
#pragma unroll
    for (int j = 0; j < 4; ++j) acc[i][j] = (f32x4){0.f, 0.f, 0.f, 0.f};

  const char* Ag = (const char*)A + (size_t)tm * 128 * Kb;
  const char* Bg = (const char*)BT + (size_t)tn * 128 * Kb;

  auto stage = [&](int buf, int t) {
#pragma unroll
    for (int i = 0; i < 4; ++i) {
      int vt = i * 256 + tid;
      int row = vt >> 3;
      int cb = (((vt & 7) << 4) ^ ((row & 7) << 4));
      gload16(Ag + (size_t)row * Kb + t * 128 + cb, smem + buf * 16384 + vt * 16);
      gload16(Bg + (size_t)row * Kb + t * 128 + cb, smem + 32768 + buf * 16384 + vt * 16);
    }
  };

  stage(0, 0);
  int cur = 0;
  const int NT = K >> 6;
  for (int t = 0; t < NT; ++t) {
    __syncthreads();
    if (t + 1 < NT) stage(cur ^ 1, t + 1);
    const char* As = smem + cur * 16384;
    const char* Bs = smem + 32768 + cur * 16384;
#pragma unroll
    for (int ks = 0; ks < 2; ++ks) {
      bf16x8 a[4], b[4];
#pragma unroll
      for (int mf = 0; mf < 4; ++mf) {
        int row = wm * 64 + mf * 16 + (lane & 15);
        int cb = (ks * 64 + ((lane >> 4) << 4)) ^ ((row & 7) << 4);
        a[mf] = *(const bf16x8*)(As + row * 128 + cb);
      }
#pragma unroll
      for (int nf = 0; nf < 4; ++nf) {
        int row = wn * 64 + nf * 16 + (lane & 15);
        int cb = (ks * 64 + ((lane >> 4) << 4)) ^ ((row & 7) << 4);
        b[nf] = *(const bf16x8*)(Bs + row * 128 + cb);
      }
#pragma unroll
      for (int mf = 0; mf < 4; ++mf)
#pragma unroll
        for (int nf = 0; nf < 4; ++nf) acc[mf][nf] = mfma16(a[mf], b[nf], acc[mf][nf]);
    }
    cur ^= 1;
  }
#pragma unroll
  for (int mf = 0; mf < 4; ++mf) {
    int row0 = tm * 128 + wm * 64 + mf * 16 + ((lane >> 4) << 2);
#pragma unroll
    for (int nf = 0; nf < 4; ++nf) {
      int col = tn * 128 + wn * 64 + nf * 16 + (lane & 15);
#pragma unroll
      for (int r = 0; r < 4; ++r) {
        float v = acc[mf][nf][r];
        if constexpr (sizeof(OutT) == 4)
          C[(size_t)(row0 + r) * N + col] = v;
        else
          C[(size_t)(row0 + r) * N + col] = f2bf(v);
      }
    }
  }
}

// ---------------------------------------------------------------------------
// Causal GQA flash attention, swapped-QK^T + in-register P, PV via K=16 MFMA.
// Block = (bx, h, b), 128 threads (2 waves), QBLK=64: q-tiles {bx, 31-bx} ->
// constant 33 K/V-tiles per block; grid 1024 = 4 blocks/CU.
//
// Key geometry: swapped QK^T output C-layout (lane holds S[q=lane&15]
// [k=4*(lane>>4)+r]) IS the A-fragment layout of v_mfma_f32_16x16x16_bf16
// (row=lane&15, k=4*(lane>>4)+j). So exp'd P feeds PV directly -- the
// cross-lane P redistribution (32 bpermute + ~100 selects per tile) is gone.
// PV output C-layout O[q=4g+r][d=nf*16+q15] is identical to the old acc.
__global__ __launch_bounds__(128, 2) void attn(const u16* __restrict__ Q,
                                               const u16* __restrict__ Kt,
                                               const u16* __restrict__ Vt,
                                               u16* __restrict__ O) {
  __shared__ __align__(16) char smem[32768];  // K dbuf [0,16K), V dbuf [16K,32K)

  const int tid = threadIdx.x, lane = tid & 63, w = tid >> 6;  // w in {0,1}
  const int q15 = lane & 15, g = lane >> 4;
  const int bx = blockIdx.x, h = blockIdx.y, b = blockIdx.z;
  const int kh = h >> 2;

  const char* Kg = (const char*)(Kt + ((size_t)(b * 8 + kh) * 2048 * 64));
  const char* Vg = (const char*)(Vt + ((size_t)(b * 8 + kh) * 64 * 2048));

  auto stageKV = [&](int buf, int kt) {
#pragma unroll
    for (int i = 0; i < 4; ++i) {
      int vt = i * 128 + tid;  // 0..511
      int row = vt >> 3;
      int cb = (((vt & 7) << 4) ^ ((row & 7) << 4));
      gload16(Kg + (size_t)(kt * 64 + row) * 128 + cb, smem + buf * 8192 + vt * 16);
      gload16(Vg + (size_t)row * 4096 + kt * 128 + cb, smem + 16384 + buf * 8192 + vt * 16);
    }
  };

#pragma unroll 1
  for (int ph = 0; ph < 2; ++ph) {
    const int qb = ph ? (31 - bx) : bx;  // q-tile of 64 rows
    const char* Qg = (const char*)(Q + (((size_t)(b * 32 + h) * 2048 + qb * 64) * 64));
    u16* Og = O + ((size_t)(b * 2048 + qb * 64) * 2048 + h * 64);

    // Q fragments (B-operand of swapped QK^T): rows = q, d-contiguous.
    bf16x8 qf[2][2];
#pragma unroll
    for (int mf2 = 0; mf2 < 2; ++mf2)
#pragma unroll
      for (int ks = 0; ks < 2; ++ks) {
        int row = w * 32 + mf2 * 16 + q15;
        qf[mf2][ks] = *(const bf16x8*)(Qg + row * 128 + ks * 64 + (g << 4));
      }

    f32x4 acc[2][4];
#pragma unroll
    for (int i = 0; i < 2; ++i)
#pragma unroll
      for (int j = 0; j < 4; ++j) acc[i][j] = (f32x4){0.f, 0.f, 0.f, 0.f};
    float m_r[2] = {-1e30f, -1e30f}, l_r[2] = {0.f, 0.f};

    __syncthreads();  // protect LDS dbuf across phases
    stageKV(0, 0);
    int cur = 0;
    const int nkt = qb + 1;
    for (int kt = 0; kt < nkt; ++kt) {
      __syncthreads();  // KV[cur] staged (compiler drains vmcnt before barrier)
      if (kt + 1 < nkt) stageKV(cur ^ 1, kt + 1);  // prefetch; drains next barrier
      const char* Ks = smem + cur * 8192;
      const char* Vs = smem + 16384 + cur * 8192;

      // swapped QK^T: st[mf2][nf] = S^T tile; lane holds
      // S[q = 16*mf2 + q15][k = 16*nf + 4*g + r]
      f32x4 st[2][4];
#pragma unroll
      for (int i = 0; i < 2; ++i)
#pragma unroll
        for (int j = 0; j < 4; ++j) st[i][j] = (f32x4){0.f, 0.f, 0.f, 0.f};
      __builtin_amdgcn_s_setprio(1);
#pragma unroll
      for (int ks = 0; ks < 2; ++ks) {
        bf16x8 kf[4];
#pragma unroll
        for (int nf = 0; nf < 4; ++nf) {
          int row = nf * 16 + q15;
          int cb = (ks * 64 + (g << 4)) ^ ((row & 7) << 4);
          kf[nf] = *(const bf16x8*)(Ks + row * 128 + cb);
        }
#pragma unroll
        for (int mf2 = 0; mf2 < 2; ++mf2)
#pragma unroll
          for (int nf = 0; nf < 4; ++nf)
            st[mf2][nf] = mfma16(kf[nf], qf[mf2][ks], st[mf2][nf]);
      }
      __builtin_amdgcn_s_setprio(0);

      // causal mask (diagonal tile only): k = kt*64+nf*16+4g+r, q = qb*64+...
      if (kt >= qb) {
#pragma unroll
        for (int mf2 = 0; mf2 < 2; ++mf2) {
          int qg = qb * 64 + w * 32 + mf2 * 16 + q15;
#pragma unroll
          for (int nf = 0; nf < 4; ++nf)
#pragma unroll
            for (int r = 0; r < 4; ++r) {
              int kg = kt * 64 + nf * 16 + 4 * g + r;
              if (kg > qg) st[mf2][nf][r] = -1e30f;
            }
        }
      }

      s16x4 pa[2][4];  // P as A-fragments of the K=16 PV MFMAs
#pragma unroll
      for (int mf2 = 0; mf2 < 2; ++mf2) {
        // row max: 15 local fmax + 2 shuffles (for the defer check)
        float vm = st[mf2][0][0];
#pragma unroll
        for (int nf = 0; nf < 4; ++nf)
#pragma unroll
          for (int r = 0; r < 4; ++r) vm = fmaxf(vm, st[mf2][nf][r]);
        vm = fmaxf(vm, __shfl_xor(vm, 16, 64));
        vm = fmaxf(vm, __shfl_xor(vm, 32, 64));

        // T13 defer-rescale: only rescale when max grew by > 8 (exp2 domain;
        // P bounded by 2^8, f32 l/acc have headroom, O/l ratio exact).
        const bool rescale = !__all(vm - m_r[mf2] <= 8.0f);
        if (rescale) {
          float mn = fmaxf(m_r[mf2], vm);
          float cr = __ocml_exp2_f32(m_r[mf2] - mn);
          m_r[mf2] = mn;
          l_r[mf2] *= cr;
          // acc rows live at q' = 4g+r; cr lives at q = l&15
          float cra[4];
#pragma unroll
          for (int r = 0; r < 4; ++r) cra[r] = __shfl(cr, 4 * g + r, 64);
#pragma unroll
          for (int nf = 0; nf < 4; ++nf)
#pragma unroll
            for (int r = 0; r < 4; ++r) acc[mf2][nf][r] *= cra[r];
        }

        // P = exp2(S - m), pack bf16 pairs (= A-frag regs); f32 row sum
        float vs = 0.f;
        const float mn = m_r[mf2];
#pragma unroll
        for (int nf = 0; nf < 4; ++nf) {
          float p0 = __ocml_exp2_f32(st[mf2][nf][0] - mn);
          float p1 = __ocml_exp2_f32(st[mf2][nf][1] - mn);
          float p2 = __ocml_exp2_f32(st[mf2][nf][2] - mn);
          float p3 = __ocml_exp2_f32(st[mf2][nf][3] - mn);
          vs += (p0 + p1) + (p2 + p3);
          u32x2 pk;
          pk.x = (u32)f2bf(p0) | ((u32)f2bf(p1) << 16);
          pk.y = (u32)f2bf(p2) | ((u32)f2bf(p3) << 16);
          pa[mf2][nf] = __builtin_bit_cast(s16x4, pk);
        }
        vs += __shfl_xor(vs, 16, 64);
        vs += __shfl_xor(vs, 32, 64);
        l_r[mf2] += vs;
      }

      // PV via K=16 MFMA, one per 16-wide k-slice (ksl == nf of P).
      // B-frag: lane holds V[k = ksl*16 + 4g + j][d = nfd*16 + q15] -- an
      // 8-byte read from the swizzled V^T row (2-way bank alias, free).
#pragma unroll
      for (int ksl = 0; ksl < 4; ++ksl) {
        s16x4 vb[4];
#pragma unroll
        for (int nfd = 0; nfd < 4; ++nfd) {
          int row = nfd * 16 + q15;
          int chunk = (2 * ksl + (g >> 1)) ^ (row & 7);
          vb[nfd] = *(const s16x4*)(Vs + row * 128 + (chunk << 4) + ((g & 1) << 3));
        }
        __builtin_amdgcn_s_setprio(1);
#pragma unroll
        for (int mf2 = 0; mf2 < 2; ++mf2)
#pragma unroll
          for (int nfd = 0; nfd < 4; ++nfd)
            acc[mf2][nfd] = mfma_k16(pa[mf2][ksl], vb[nfd], acc[mf2][nfd]);
        __builtin_amdgcn_s_setprio(0);
      }
      cur ^= 1;
    }

    // epilogue: normalize by l (lives at q = l&15; acc rows at q' = 4g+r)
#pragma unroll
    for (int mf2 = 0; mf2 < 2; ++mf2) {
      float la[4];
#pragma unroll
      for (int r = 0; r < 4; ++r) la[r] = __shfl(l_r[mf2], 4 * g + r, 64);
#pragma unroll
      for (int r = 0; r < 4; ++r) {
        int row = w * 32 + mf2 * 16 + 4 * g + r;
        float li = 1.f / la[r];
#pragma unroll
        for (int nf = 0; nf < 4; ++nf)
          Og[(size_t)row * 2048 + nf * 16 + q15] = f2bf(acc[mf2][nf][r] * li);
      }
    }
  }
}

// ---------------------------------------------------------------------------
extern "C" void kernel_launch(void* const* d_in, const int* in_sizes, int n_in,
                              void* d_out, int out_size, void* d_ws, size_t ws_size,
                              hipStream_t stream) {
  const float* x = (const float*)d_in[0];
  const float* fc = (const float*)d_in[1];
  const float* fs = (const float*)d_in[2];
  const float* wq = (const float*)d_in[3];
  const float* wk = (const float*)d_in[4];
  const float* wv = (const float*)d_in[5];
  const float* wo = (const float*)d_in[6];
  float* out = (float*)d_out;
  char* ws = (char*)d_ws;

  // Compact workspace layout (60 MB total):
  u16* xb    = (u16*)(ws);                 // [4096][2048] 16 MB  (reused as Q)
  u16* qkv   = (u16*)(ws + 16777216);      // [4096][3072] 24 MB  (reused as O)
  u16* woT   = (u16*)(ws + 41943040);      // [2048][2048]  8 MB
  u16* wqkvT = (u16*)(ws + 50331648);      // [3072][2048] 12 MB (dead after QKV GEMM)
  u16* Kbuf  = (u16*)(ws + 50331648);      // [2][8][2048][64] 4 MB (overlays wqkvT)
  u16* Vtb   = (u16*)(ws + 54525952);      // [2][8][64][2048] 4 MB (overlays wqkvT)
  u16* Qbuf = xb;
  u16* Obuf = qkv;

  dim3 tb(32, 8);
  cvt_x<<<dim3(8192), dim3(256), 0, stream>>>(x, xb);
  tconv<<<dim3(64, 64), tb, 0, stream>>>(wq, wqkvT, 2048, 0, 2048);
  tconv<<<dim3(16, 64), tb, 0, stream>>>(wk, wqkvT, 512, 2048, 2048);
  tconv<<<dim3(16, 64), tb, 0, stream>>>(wv, wqkvT, 512, 2560, 2048);
  tconv<<<dim3(64, 64), tb, 0, stream>>>(wo, woT, 2048, 0, 2048);
  gemm_bt<u16><<<dim3(24, 32), dim3(256), 0, stream>>>(xb, wqkvT, qkv, 4096, 3072, 2048);
  rope_qk<<<dim3(20480), dim3(256), 0, stream>>>(qkv, fc, fs, Qbuf, Kbuf);
  vtrans<<<dim3(64, 2, 16), tb, 0, stream>>>(qkv, Vtb);
  attn<<<dim3(16, 32, 2), dim3(128), 0, stream>>>(Qbuf, Kbuf, Vtb, Obuf);
  gemm_bt<float><<<dim3(16, 32), dim3(256), 0, stream>>>(Obuf, woT, out, 4096, 2048, 2048);
}

// Round 7
// 221.312 us; speedup vs baseline: 1.6699x; 1.0429x over previous
//
#include <hip/hip_runtime.h>

typedef unsigned short u16;
typedef unsigned int u32;
typedef __bf16 bf16x4 __attribute__((ext_vector_type(4)));
typedef __bf16 bf16x8 __attribute__((ext_vector_type(8)));
typedef float f32x4 __attribute__((ext_vector_type(4)));
typedef u32 u32x2 __attribute__((ext_vector_type(2)));
typedef u32 u32x4 __attribute__((ext_vector_type(4)));
typedef short s16x4 __attribute__((ext_vector_type(4)));

struct __align__(4) U16x2 { u16 x, y; };
struct __align__(8) U16x4 { u16 x, y, z, w; };

#define DEV static __device__ __forceinline__

extern "C" __device__ float __ocml_exp2_f32(float);
#if __has_builtin(__builtin_amdgcn_exp2f)
#define EXP2(x) __builtin_amdgcn_exp2f(x)
#else
#define EXP2(x) __ocml_exp2_f32(x)
#endif

DEV u16 f2bf(float f) {
  __bf16 h = (__bf16)f;
  return __builtin_bit_cast(u16, h);
}
DEV float bf2f(u16 u) { return __uint_as_float(((u32)u) << 16); }
DEV u32 pk2bf(float lo, float hi) { return (u32)f2bf(lo) | ((u32)f2bf(hi) << 16); }

DEV void gload16(const void* g, void* l) {
  __builtin_amdgcn_global_load_lds((const __attribute__((address_space(1))) char*)g,
                                   (__attribute__((address_space(3))) char*)l, 16, 0, 0);
}

DEV f32x4 mfma16(bf16x8 a, bf16x8 b, f32x4 c) {
  return __builtin_amdgcn_mfma_f32_16x16x32_bf16(a, b, c, 0, 0, 0);
}

// K=16 MFMA: A-frag lane holds row=lane&15, k=4*(lane>>4)+j -- identical to
// the C-layout of a previous MFMA, so exp'd S feeds PV with zero lane motion.
DEV f32x4 mfma_k16(s16x4 a, s16x4 b, f32x4 c) {
#if __has_builtin(__builtin_amdgcn_mfma_f32_16x16x16bf16_1k)
  return __builtin_amdgcn_mfma_f32_16x16x16bf16_1k(a, b, c, 0, 0, 0);
#else
  f32x4 d;
  asm("v_mfma_f32_16x16x16_bf16 %0, %1, %2, %3"
      : "=v"(d)
      : "v"(a), "v"(b), "0"(c));
  return d;
#endif
}

// ---------------------------------------------------------------------------
// x fp32 -> bf16, 4 elems/thread
__global__ __launch_bounds__(256) void cvt_x(const float* __restrict__ x, u16* __restrict__ xb) {
  int i = blockIdx.x * 256 + threadIdx.x;
  float4 v = ((const float4*)x)[i];
  U16x4 o;
  o.x = f2bf(v.x); o.y = f2bf(v.y); o.z = f2bf(v.z); o.w = f2bf(v.w);
  ((U16x4*)xb)[i] = o;
}

// ---------------------------------------------------------------------------
// fp32 [R][C] -> bf16 dst[nOff + c][r] (transposed), ldd = R
__global__ __launch_bounds__(256) void tconv(const float* __restrict__ src, u16* __restrict__ dst,
                                             int C, int nOff, int ldd) {
  __shared__ float t[32][33];
  int bx = blockIdx.x, by = blockIdx.y;
  int tx = threadIdx.x, ty = threadIdx.y;
#pragma unroll
  for (int j = 0; j < 4; ++j)
    t[ty + 8 * j][tx] = src[(size_t)(by * 32 + ty + 8 * j) * C + bx * 32 + tx];
  __syncthreads();
#pragma unroll
  for (int j = 0; j < 4; ++j)
    dst[(size_t)(nOff + bx * 32 + ty + 8 * j) * ldd + by * 32 + tx] = f2bf(t[tx][ty + 8 * j]);
}

// ---------------------------------------------------------------------------
// bf16 qkv v-slice -> Vt[(b*8+kh)*64+d][s'], with s' k-interleaved within each
// 32-kv block: slot(k) = ((k&15)>>2)*8 + (k>>4)*4 + (k&3), so attn's PV can
// read both K=16 B-fragments as halves of one ds_read_b128.
__global__ __launch_bounds__(256) void vtrans(const u16* __restrict__ qkv, u16* __restrict__ Vt) {
  __shared__ u16 t[32][33];
  int bx = blockIdx.x, by = blockIdx.y, bz = blockIdx.z;
  int tx = threadIdx.x, ty = threadIdx.y;
  int b = bz >> 3, kh = bz & 7;
  const u16* src = qkv + (size_t)(b * 2048 + bx * 32) * 3072 + 2560 + kh * 64 + by * 32;
#pragma unroll
  for (int j = 0; j < 4; ++j) t[ty + 8 * j][tx] = src[(size_t)(ty + 8 * j) * 3072 + tx];
  __syncthreads();
  u16* dst = Vt + ((size_t)bz * 64 + by * 32) * 2048 + bx * 32;
  int pc = ((tx & 15) >> 2) * 8 + ((tx >> 4) << 2) + (tx & 3);  // interleave slot
#pragma unroll
  for (int j = 0; j < 4; ++j) dst[(size_t)(ty + 8 * j) * 2048 + pc] = t[tx][ty + 8 * j];
}

// ---------------------------------------------------------------------------
// RoPE on q,k heads of qkv[4096][3072]; writes Q[b][h][s][64] (pre-scaled by
// 0.125*log2(e) so attn softmax runs in the exp2 domain), K[b][kh][s][64].
__global__ __launch_bounds__(256) void rope_qk(const u16* __restrict__ qkv,
                                               const float* __restrict__ fc,
                                               const float* __restrict__ fs,
                                               u16* __restrict__ Qo, u16* __restrict__ Ko) {
  int t = blockIdx.x * 256 + threadIdx.x;  // 5,242,880 total
  int d2 = t & 31;
  int rest = t >> 5;
  int h40 = rest % 40;
  int bs = rest / 40;  // b*2048 + s
  int s = bs & 2047;
  int b = bs >> 11;
  const u16* src;
  u16* dst;
  float qscale;
  if (h40 < 32) {
    src = qkv + (size_t)bs * 3072 + h40 * 64 + 2 * d2;
    dst = Qo + (((size_t)(b * 32 + h40) * 2048 + s) * 64 + 2 * d2);
    qscale = 0.18033688011112042f;  // 0.125 * log2(e)
  } else {
    int kh = h40 - 32;
    src = qkv + (size_t)bs * 3072 + 2048 + kh * 64 + 2 * d2;
    dst = Ko + (((size_t)(b * 8 + kh) * 2048 + s) * 64 + 2 * d2);
    qscale = 1.0f;
  }
  U16x2 v = *(const U16x2*)src;
  float xr = bf2f(v.x), xi = bf2f(v.y);
  float c = fc[s * 32 + d2] * qscale, sn = fs[s * 32 + d2] * qscale;
  U16x2 o;
  o.x = f2bf(xr * c - xi * sn);
  o.y = f2bf(xr * sn + xi * c);
  *(U16x2*)dst = o;
}

// ---------------------------------------------------------------------------
// C[M][N] = A[M][K] * BT[N][K]^T  (bf16 in, OutT out). 128x128 tile, BK=64,
// 4 waves (2x2), swizzled LDS, double-buffered global_load_lds staging.
template <typename OutT>
__global__ __launch_bounds__(256, 2) void gemm_bt(const u16* __restrict__ A,
                                                  const u16* __restrict__ BT,
                                                  OutT* __restrict__ C,
                                                  int M, int N, int K) {
  __shared__ __align__(16) char smem[65536];  // As[2]@0, Bs[2]@32768 (16384 each)
  const int tid = threadIdx.x;
  const int lane = tid & 63;
  const int wm = (tid >> 7) & 1, wn = (tid >> 6) & 1;
  const int tm = blockIdx.y, tn = blockIdx.x;
  const int Kb = K * 2;

  f32x4 acc[4][4];
#pragma unroll
  for (int i = 0; i < 4; ++i)
#pragma unroll
    for (int j = 0; j < 4; ++j) acc[i][j] = (f32x4){0.f, 0.f, 0.f, 0.f};

  const char* Ag = (const char*)A + (size_t)tm * 128 * Kb;
  const char* Bg = (const char*)BT + (size_t)tn * 128 * Kb;

  auto stage = [&](int buf, int t) {
#pragma unroll
    for (int i = 0; i < 4; ++i) {
      int vt = i * 256 + tid;
      int row = vt >> 3;
      int cb = (((vt & 7) << 4) ^ ((row & 7) << 4));
      gload16(Ag + (size_t)row * Kb + t * 128 + cb, smem + buf * 16384 + vt * 16);
      gload16(Bg + (size_t)row * Kb + t * 128 + cb, smem + 32768 + buf * 16384 + vt * 16);
    }
  };

  stage(0, 0);
  int cur = 0;
  const int NT = K >> 6;
  for (int t = 0; t < NT; ++t) {
    __syncthreads();
    if (t + 1 < NT) stage(cur ^ 1, t + 1);
    const char* As = smem + cur * 16384;
    const char* Bs = smem + 32768 + cur * 16384;
#pragma unroll
    for (int ks = 0; ks < 2; ++ks) {
      bf16x8 a[4], b[4];
#pragma unroll
      for (int mf = 0; mf < 4; ++mf) {
        int row = wm * 64 + mf * 16 + (lane & 15);
        int cb = (ks * 64 + ((lane >> 4) << 4)) ^ ((row & 7) << 4);
        a[mf] = *(const bf16x8*)(As + row * 128 + cb);
      }
#pragma unroll
      for (int nf = 0; nf < 4; ++nf) {
        int row = wn * 64 + nf * 16 + (lane & 15);
        int cb = (ks * 64 + ((lane >> 4) << 4)) ^ ((row & 7) << 4);
        b[nf] = *(const bf16x8*)(Bs + row * 128 + cb);
      }
#pragma unroll
      for (int mf = 0; mf < 4; ++mf)
#pragma unroll
        for (int nf = 0; nf < 4; ++nf) acc[mf][nf] = mfma16(a[mf], b[nf], acc[mf][nf]);
    }
    cur ^= 1;
  }
#pragma unroll
  for (int mf = 0; mf < 4; ++mf) {
    int row0 = tm * 128 + wm * 64 + mf * 16 + ((lane >> 4) << 2);
#pragma unroll
    for (int nf = 0; nf < 4; ++nf) {
      int col = tn * 128 + wn * 64 + nf * 16 + (lane & 15);
#pragma unroll
      for (int r = 0; r < 4; ++r) {
        float v = acc[mf][nf][r];
        if constexpr (sizeof(OutT) == 4)
          C[(size_t)(row0 + r) * N + col] = v;
        else
          C[(size_t)(row0 + r) * N + col] = f2bf(v);
      }
    }
  }
}

// ---------------------------------------------------------------------------
// Causal GQA flash attention: dual-tile waves, swapped QK^T, in-register P,
// PV via K=16 MFMA, KVBLK=32, fully-resident grid.
// Block = (bx, h, b), 128 threads: owns q-tiles {63-bx (heavy), bx (light)},
// QBLK=32. Wave w holds rows [Qt*32+w*16, +16) of BOTH tiles; one merged kv
// loop kt = 0..63-bx; light tile active while kt <= bx. Every block = 65
// work-units -> perfectly balanced; 2048 blocks x 16KB LDS = 8 blocks/CU
// all resident = 4 waves/SIMD.
__global__ __launch_bounds__(128, 4) void attn(const u16* __restrict__ Q,
                                               const u16* __restrict__ Kt,
                                               const u16* __restrict__ Vt,
                                               u16* __restrict__ O) {
  __shared__ __align__(16) char smem[16384];  // per buf: K 4KB + V 4KB

  const int tid = threadIdx.x, lane = tid & 63, w = tid >> 6;  // w in {0,1}
  const int q15 = lane & 15, g = lane >> 4;
  const int bx = blockIdx.x, h = blockIdx.y, b = blockIdx.z;
  const int kh = h >> 2;
  const int QT0 = 63 - bx, QT1 = bx;  // heavy, light q-tiles (32 rows each)

  const char* Qg = (const char*)(Q + ((size_t)(b * 32 + h) * 2048) * 64);
  const char* Kg = (const char*)(Kt + ((size_t)(b * 8 + kh) * 2048 * 64));
  const char* Vg = (const char*)(Vt + ((size_t)(b * 8 + kh) * 64 * 2048));

  // Q fragments (B-operand of swapped QK^T), both tiles
  bf16x8 qf0[2], qf1[2];
#pragma unroll
  for (int ks = 0; ks < 2; ++ks) {
    int r0 = QT0 * 32 + w * 16 + q15;
    int r1 = QT1 * 32 + w * 16 + q15;
    qf0[ks] = *(const bf16x8*)(Qg + (size_t)r0 * 128 + ks * 64 + (g << 4));
    qf1[ks] = *(const bf16x8*)(Qg + (size_t)r1 * 128 + ks * 64 + (g << 4));
  }

  f32x4 acc0[4], acc1[4];
#pragma unroll
  for (int j = 0; j < 4; ++j) {
    acc0[j] = (f32x4){0.f, 0.f, 0.f, 0.f};
    acc1[j] = (f32x4){0.f, 0.f, 0.f, 0.f};
  }
  float m0 = -1e30f, m1 = -1e30f, l0 = 0.f, l1 = 0.f;
  const f32x4 FZ = (f32x4){0.f, 0.f, 0.f, 0.f};

  auto stageKV = [&](int buf, int kt) {
#pragma unroll
    for (int i = 0; i < 2; ++i) {
      int vt = i * 128 + tid;  // 0..255
      int r = vt >> 3, ck = vt & 7;  // K: 32 rows x 8 chunks, swz ^(r&7)
      gload16(Kg + (size_t)(kt * 32 + r) * 128 + (((ck ^ r) & 7) << 4),
              smem + buf * 8192 + vt * 16);
      int d = vt >> 2, cv = vt & 3;  // V: 64 rows x 4 chunks, swz ^((d>>1)&3)
      gload16(Vg + (size_t)d * 4096 + kt * 64 + (((cv ^ (d >> 1)) & 3) << 4),
              smem + buf * 8192 + 4096 + vt * 16);
    }
  };

  stageKV(0, 0);
  int cur = 0;
  const int nkt = QT0 + 1;
  for (int kt = 0; kt < nkt; ++kt) {
    __syncthreads();  // KV[cur] staged (compiler drains vmcnt before barrier)
    if (kt + 1 < nkt) stageKV(cur ^ 1, kt + 1);
    const char* Ks = smem + cur * 8192;
    const char* Vs = smem + cur * 8192 + 4096;
    const bool la = (kt <= QT1);  // light tile active

    // K fragments (A-operand), shared by both tiles
    bf16x8 kf[2][2];  // [ks][nf]
#pragma unroll
    for (int ks = 0; ks < 2; ++ks)
#pragma unroll
      for (int nf = 0; nf < 2; ++nf) {
        int r = nf * 16 + q15;
        int c = (4 * ks + g) ^ (r & 7);
        kf[ks][nf] = *(const bf16x8*)(Ks + r * 128 + (c << 4));
      }

    // swapped QK^T: lane holds S[q = Qt*32+w*16+q15][k = kt*32+nf*16+4g+r]
    f32x4 st0[2], st1[2];
    __builtin_amdgcn_s_setprio(1);
#pragma unroll
    for (int nf = 0; nf < 2; ++nf) {
      st0[nf] = mfma16(kf[0][nf], qf0[0], FZ);
      st0[nf] = mfma16(kf[1][nf], qf0[1], st0[nf]);
    }
    if (la) {
#pragma unroll
      for (int nf = 0; nf < 2; ++nf) {
        st1[nf] = mfma16(kf[0][nf], qf1[0], FZ);
        st1[nf] = mfma16(kf[1][nf], qf1[1], st1[nf]);
      }
    }
    __builtin_amdgcn_s_setprio(0);

    // causal mask on each tile's diagonal step
    if (kt == QT0) {
      int qg = QT0 * 32 + w * 16 + q15;
#pragma unroll
      for (int nf = 0; nf < 2; ++nf)
#pragma unroll
        for (int r = 0; r < 4; ++r) {
          int kg = kt * 32 + nf * 16 + 4 * g + r;
          if (kg > qg) st0[nf][r] = -1e30f;
        }
    }
    if (la && kt == QT1) {
      int qg = QT1 * 32 + w * 16 + q15;
#pragma unroll
      for (int nf = 0; nf < 2; ++nf)
#pragma unroll
        for (int r = 0; r < 4; ++r) {
          int kg = kt * 32 + nf * 16 + 4 * g + r;
          if (kg > qg) st1[nf][r] = -1e30f;
        }
    }

    // softmax (exp2 domain, T13 defer-rescale), P packs directly into A-frags
    s16x4 pa0[2], pa1[2];
#pragma unroll
    for (int t = 0; t < 2; ++t) {
      if (t == 1 && !la) break;
      f32x4* st = (t == 0) ? st0 : st1;
      float& m_r = (t == 0) ? m0 : m1;
      float& l_r = (t == 0) ? l0 : l1;
      f32x4* accT = (t == 0) ? acc0 : acc1;
      s16x4* pa = (t == 0) ? pa0 : pa1;

      float vm = fmaxf(fmaxf(fmaxf(st[0][0], st[0][1]), fmaxf(st[0][2], st[0][3])),
                       fmaxf(fmaxf(st[1][0], st[1][1]), fmaxf(st[1][2], st[1][3])));
      vm = fmaxf(vm, __shfl_xor(vm, 16, 64));
      vm = fmaxf(vm, __shfl_xor(vm, 32, 64));
      const bool resc = !__all(vm - m_r <= 8.0f);
      if (resc) {
        float mn = fmaxf(m_r, vm);
        float cr = EXP2(m_r - mn);
        m_r = mn;
        l_r *= cr;
        float cra[4];
#pragma unroll
        for (int r = 0; r < 4; ++r) cra[r] = __shfl(cr, 4 * g + r, 64);
#pragma unroll
        for (int nfd = 0; nfd < 4; ++nfd)
#pragma unroll
          for (int r = 0; r < 4; ++r) accT[nfd][r] *= cra[r];
      }
      float vs = 0.f;
#pragma unroll
      for (int nf = 0; nf < 2; ++nf) {
        float p0 = EXP2(st[nf][0] - m_r);
        float p1 = EXP2(st[nf][1] - m_r);
        float p2 = EXP2(st[nf][2] - m_r);
        float p3 = EXP2(st[nf][3] - m_r);
        vs += (p0 + p1) + (p2 + p3);
        u32x2 pk;
        pk.x = pk2bf(p0, p1);
        pk.y = pk2bf(p2, p3);
        pa[nf] = __builtin_bit_cast(s16x4, pk);
      }
      vs += __shfl_xor(vs, 16, 64);
      vs += __shfl_xor(vs, 32, 64);
      l_r += vs;
    }

    // PV: one b128 per nfd (k-interleaved V) yields both K=16 B-frag halves.
#pragma unroll
    for (int nfd = 0; nfd < 4; ++nfd) {
      int d = nfd * 16 + q15;
      int c = (g ^ (d >> 1)) & 3;
      bf16x8 wv = *(const bf16x8*)(Vs + d * 64 + (c << 4));
      u32x4 W = __builtin_bit_cast(u32x4, wv);
      u32x2 wlo, whi;
      wlo.x = W.x; wlo.y = W.y; whi.x = W.z; whi.y = W.w;
      s16x4 v0 = __builtin_bit_cast(s16x4, wlo);  // k = kt*32 + 4g + j
      s16x4 v1 = __builtin_bit_cast(s16x4, whi);  // k = kt*32 + 16 + 4g + j
      __builtin_amdgcn_s_setprio(1);
      acc0[nfd] = mfma_k16(pa0[0], v0, acc0[nfd]);
      acc0[nfd] = mfma_k16(pa0[1], v1, acc0[nfd]);
      if (la) {
        acc1[nfd] = mfma_k16(pa1[0], v0, acc1[nfd]);
        acc1[nfd] = mfma_k16(pa1[1], v1, acc1[nfd]);
      }
      __builtin_amdgcn_s_setprio(0);
    }
    cur ^= 1;
  }

  // epilogue: normalize (l lives at q = lane&15; acc rows at q' = 4g+r)
#pragma unroll
  for (int t = 0; t < 2; ++t) {
    float l_r = (t == 0) ? l0 : l1;
    f32x4* accT = (t == 0) ? acc0 : acc1;
    int qt = (t == 0) ? QT0 : QT1;
    u16* Og = O + ((size_t)(b * 2048 + qt * 32 + w * 16) * 2048 + h * 64);
    float la4[4];
#pragma unroll
    for (int r = 0; r < 4; ++r) la4[r] = __shfl(l_r, 4 * g + r, 64);
#pragma unroll
    for (int r = 0; r < 4; ++r) {
      float li = 1.f / la4[r];
#pragma unroll
      for (int nfd = 0; nfd < 4; ++nfd)
        Og[(size_t)(4 * g + r) * 2048 + nfd * 16 + q15] = f2bf(accT[nfd][r] * li);
    }
  }
}

// ---------------------------------------------------------------------------
extern "C" void kernel_launch(void* const* d_in, const int* in_sizes, int n_in,
                              void* d_out, int out_size, void* d_ws, size_t ws_size,
                              hipStream_t stream) {
  const float* x = (const float*)d_in[0];
  const float* fc = (const float*)d_in[1];
  const float* fs = (const float*)d_in[2];
  const float* wq = (const float*)d_in[3];
  const float* wk = (const float*)d_in[4];
  const float* wv = (const float*)d_in[5];
  const float* wo = (const float*)d_in[6];
  float* out = (float*)d_out;
  char* ws = (char*)d_ws;

  // Compact workspace layout (60 MB total):
  u16* xb    = (u16*)(ws);                 // [4096][2048] 16 MB  (reused as Q)
  u16* qkv   = (u16*)(ws + 16777216);      // [4096][3072] 24 MB  (reused as O)
  u16* woT   = (u16*)(ws + 41943040);      // [2048][2048]  8 MB
  u16* wqkvT = (u16*)(ws + 50331648);      // [3072][2048] 12 MB (dead after QKV GEMM)
  u16* Kbuf  = (u16*)(ws + 50331648);      // [2][8][2048][64] 4 MB (overlays wqkvT)
  u16* Vtb   = (u16*)(ws + 54525952);      // [2][8][64][2048] 4 MB (overlays wqkvT)
  u16* Qbuf = xb;
  u16* Obuf = qkv;

  dim3 tb(32, 8);
  cvt_x<<<dim3(8192), dim3(256), 0, stream>>>(x, xb);
  tconv<<<dim3(64, 64), tb, 0, stream>>>(wq, wqkvT, 2048, 0, 2048);
  tconv<<<dim3(16, 64), tb, 0, stream>>>(wk, wqkvT, 512, 2048, 2048);
  tconv<<<dim3(16, 64), tb, 0, stream>>>(wv, wqkvT, 512, 2560, 2048);
  tconv<<<dim3(64, 64), tb, 0, stream>>>(wo, woT, 2048, 0, 2048);
  gemm_bt<u16><<<dim3(24, 32), dim3(256), 0, stream>>>(xb, wqkvT, qkv, 4096, 3072, 2048);
  rope_qk<<<dim3(20480), dim3(256), 0, stream>>>(qkv, fc, fs, Qbuf, Kbuf);
  vtrans<<<dim3(64, 2, 16), tb, 0, stream>>>(qkv, Vtb);
  attn<<<dim3(32, 32, 2), dim3(128), 0, stream>>>(Qbuf, Kbuf, Vtb, Obuf);
  gemm_bt<float><<<dim3(16, 32), dim3(256), 0, stream>>>(Obuf, woT, out, 4096, 2048, 2048);
}

// Round 8
// 219.489 us; speedup vs baseline: 1.6837x; 1.0083x over previous
//
#include <hip/hip_runtime.h>

typedef unsigned short u16;
typedef unsigned int u32;
typedef __bf16 bf16x4 __attribute__((ext_vector_type(4)));
typedef __bf16 bf16x8 __attribute__((ext_vector_type(8)));
typedef float f32x4 __attribute__((ext_vector_type(4)));
typedef u32 u32x4 __attribute__((ext_vector_type(4)));

struct __align__(4) U16x2 { u16 x, y; };
struct __align__(8) U16x4 { u16 x, y, z, w; };

#define DEV static __device__ __forceinline__

extern "C" __device__ float __ocml_exp2_f32(float);
#if __has_builtin(__builtin_amdgcn_exp2f)
#define EXP2(x) __builtin_amdgcn_exp2f(x)
#else
#define EXP2(x) __ocml_exp2_f32(x)
#endif

DEV u16 f2bf(float f) {
  __bf16 h = (__bf16)f;
  return __builtin_bit_cast(u16, h);
}
DEV float bf2f(u16 u) { return __uint_as_float(((u32)u) << 16); }
DEV u32 pk2bf(float lo, float hi) { return (u32)f2bf(lo) | ((u32)f2bf(hi) << 16); }

DEV void gload16(const void* g, void* l) {
  __builtin_amdgcn_global_load_lds((const __attribute__((address_space(1))) char*)g,
                                   (__attribute__((address_space(3))) char*)l, 16, 0, 0);
}

DEV f32x4 mfma16(bf16x8 a, bf16x8 b, f32x4 c) {
  return __builtin_amdgcn_mfma_f32_16x16x32_bf16(a, b, c, 0, 0, 0);
}

// ---------------------------------------------------------------------------
// x fp32 -> bf16, 4 elems/thread
__global__ __launch_bounds__(256) void cvt_x(const float* __restrict__ x, u16* __restrict__ xb) {
  int i = blockIdx.x * 256 + threadIdx.x;
  float4 v = ((const float4*)x)[i];
  U16x4 o;
  o.x = f2bf(v.x); o.y = f2bf(v.y); o.z = f2bf(v.z); o.w = f2bf(v.w);
  ((U16x4*)xb)[i] = o;
}

// ---------------------------------------------------------------------------
// fp32 [R][C] -> bf16 dst[nOff + c][r] (transposed), ldd = R
__global__ __launch_bounds__(256) void tconv(const float* __restrict__ src, u16* __restrict__ dst,
                                             int C, int nOff, int ldd) {
  __shared__ float t[32][33];
  int bx = blockIdx.x, by = blockIdx.y;
  int tx = threadIdx.x, ty = threadIdx.y;
#pragma unroll
  for (int j = 0; j < 4; ++j)
    t[ty + 8 * j][tx] = src[(size_t)(by * 32 + ty + 8 * j) * C + bx * 32 + tx];
  __syncthreads();
#pragma unroll
  for (int j = 0; j < 4; ++j)
    dst[(size_t)(nOff + bx * 32 + ty + 8 * j) * ldd + by * 32 + tx] = f2bf(t[tx][ty + 8 * j]);
}

// ---------------------------------------------------------------------------
// bf16 qkv v-slice [b*2048+s][2560+kh*64+d] -> Vt[(b*8+kh)*64+d][s]
// (plain transpose; attn consumes natural kv order with the K=32 PV).
__global__ __launch_bounds__(256) void vtrans(const u16* __restrict__ qkv, u16* __restrict__ Vt) {
  __shared__ u16 t[32][33];
  int bx = blockIdx.x, by = blockIdx.y, bz = blockIdx.z;
  int tx = threadIdx.x, ty = threadIdx.y;
  int b = bz >> 3, kh = bz & 7;
  const u16* src = qkv + (size_t)(b * 2048 + bx * 32) * 3072 + 2560 + kh * 64 + by * 32;
#pragma unroll
  for (int j = 0; j < 4; ++j) t[ty + 8 * j][tx] = src[(size_t)(ty + 8 * j) * 3072 + tx];
  __syncthreads();
  u16* dst = Vt + ((size_t)bz * 64 + by * 32) * 2048 + bx * 32;
#pragma unroll
  for (int j = 0; j < 4; ++j) dst[(size_t)(ty + 8 * j) * 2048 + tx] = t[tx][ty + 8 * j];
}

// ---------------------------------------------------------------------------
// RoPE on q,k heads of qkv[4096][3072]; writes Q[b][h][s][64] (pre-scaled by
// 0.125*log2(e) so attn softmax runs in the exp2 domain), K[b][kh][s][64].
__global__ __launch_bounds__(256) void rope_qk(const u16* __restrict__ qkv,
                                               const float* __restrict__ fc,
                                               const float* __restrict__ fs,
                                               u16* __restrict__ Qo, u16* __restrict__ Ko) {
  int t = blockIdx.x * 256 + threadIdx.x;  // 5,242,880 total
  int d2 = t & 31;
  int rest = t >> 5;
  int h40 = rest % 40;
  int bs = rest / 40;  // b*2048 + s
  int s = bs & 2047;
  int b = bs >> 11;
  const u16* src;
  u16* dst;
  float qscale;
  if (h40 < 32) {
    src = qkv + (size_t)bs * 3072 + h40 * 64 + 2 * d2;
    dst = Qo + (((size_t)(b * 32 + h40) * 2048 + s) * 64 + 2 * d2);
    qscale = 0.18033688011112042f;  // 0.125 * log2(e)
  } else {
    int kh = h40 - 32;
    src = qkv + (size_t)bs * 3072 + 2048 + kh * 64 + 2 * d2;
    dst = Ko + (((size_t)(b * 8 + kh) * 2048 + s) * 64 + 2 * d2);
    qscale = 1.0f;
  }
  U16x2 v = *(const U16x2*)src;
  float xr = bf2f(v.x), xi = bf2f(v.y);
  float c = fc[s * 32 + d2] * qscale, sn = fs[s * 32 + d2] * qscale;
  U16x2 o;
  o.x = f2bf(xr * c - xi * sn);
  o.y = f2bf(xr * sn + xi * c);
  *(U16x2*)dst = o;
}

// ---------------------------------------------------------------------------
// C[M][N] = A[M][K] * BT[N][K]^T  (bf16 in, OutT out). 128x128 tile, BK=64,
// 4 waves (2x2), swizzled LDS, double-buffered global_load_lds staging.
template <typename OutT>
__global__ __launch_bounds__(256, 2) void gemm_bt(const u16* __restrict__ A,
                                                  const u16* __restrict__ BT,
                                                  OutT* __restrict__ C,
                                                  int M, int N, int K) {
  __shared__ __align__(16) char smem[65536];  // As[2]@0, Bs[2]@32768 (16384 each)
  const int tid = threadIdx.x;
  const int lane = tid & 63;
  const int wm = (tid >> 7) & 1, wn = (tid >> 6) & 1;
  const int tm = blockIdx.y, tn = blockIdx.x;
  const int Kb = K * 2;

  f32x4 acc[4][4];
#pragma unroll
  for (int i = 0; i < 4; ++i)
#pragma unroll
    for (int j = 0; j < 4; ++j) acc[i][j] = (f32x4){0.f, 0.f, 0.f, 0.f};

  const char* Ag = (const char*)A + (size_t)tm * 128 * Kb;
  const char* Bg = (const char*)BT + (size_t)tn * 128 * Kb;

  auto stage = [&](int buf, int t) {
#pragma unroll
    for (int i = 0; i < 4; ++i) {
      int vt = i * 256 + tid;
      int row = vt >> 3;
      int cb = (((vt & 7) << 4) ^ ((row & 7) << 4));
      gload16(Ag + (size_t)row * Kb + t * 128 + cb, smem + buf * 16384 + vt * 16);
      gload16(Bg + (size_t)row * Kb + t * 128 + cb, smem + 32768 + buf * 16384 + vt * 16);
    }
  };

  stage(0, 0);
  int cur = 0;
  const int NT = K >> 6;
  for (int t = 0; t < NT; ++t) {
    __syncthreads();
    if (t + 1 < NT) stage(cur ^ 1, t + 1);
    const char* As = smem + cur * 16384;
    const char* Bs = smem + 32768 + cur * 16384;
#pragma unroll
    for (int ks = 0; ks < 2; ++ks) {
      bf16x8 a[4], b[4];
#pragma unroll
      for (int mf = 0; mf < 4; ++mf) {
        int row = wm * 64 + mf * 16 + (lane & 15);
        int cb = (ks * 64 + ((lane >> 4) << 4)) ^ ((row & 7) << 4);
        a[mf] = *(const bf16x8*)(As + row * 128 + cb);
      }
#pragma unroll
      for (int nf = 0; nf < 4; ++nf) {
        int row = wn * 64 + nf * 16 + (lane & 15);
        int cb = (ks * 64 + ((lane >> 4) << 4)) ^ ((row & 7) << 4);
        b[nf] = *(const bf16x8*)(Bs + row * 128 + cb);
      }
#pragma unroll
      for (int mf = 0; mf < 4; ++mf)
#pragma unroll
        for (int nf = 0; nf < 4; ++nf) acc[mf][nf] = mfma16(a[mf], b[nf], acc[mf][nf]);
    }
    cur ^= 1;
  }
#pragma unroll
  for (int mf = 0; mf < 4; ++mf) {
    int row0 = tm * 128 + wm * 64 + mf * 16 + ((lane >> 4) << 2);
#pragma unroll
    for (int nf = 0; nf < 4; ++nf) {
      int col = tn * 128 + wn * 64 + nf * 16 + (lane & 15);
#pragma unroll
      for (int r = 0; r < 4; ++r) {
        float v = acc[mf][nf][r];
        if constexpr (sizeof(OutT) == 4)
          C[(size_t)(row0 + r) * N + col] = v;
        else
          C[(size_t)(row0 + r) * N + col] = f2bf(v);
      }
    }
  }
}

// ---------------------------------------------------------------------------
// Causal GQA flash attention: dual-tile waves, swapped QK^T, in-register P,
// PV via K=32 MFMA through a kv-permuted K tile, KVBLK=32, fully resident.
//
// Permutation trick: attention is permutation-invariant along kv. K rows are
// staged into LDS row rho = nf*16+4g+r holding global kv kappa = 8g+4nf+r.
// QK^T's C-layout slot (nf,g,r) then holds S[q][k=8g+4nf+r], so the exp'd P
// packed in register order j=4nf+r IS the 16x16x32 A-fragment (k=8g+j) --
// PV needs zero cross-lane motion and half the MFMA instructions of K=16.
// V stays in natural kv order (B-frag k=8g+j reads 16 contiguous bytes).
__global__ __launch_bounds__(128, 4) void attn(const u16* __restrict__ Q,
                                               const u16* __restrict__ Kt,
                                               const u16* __restrict__ Vt,
                                               u16* __restrict__ O) {
  __shared__ __align__(16) char smem[16384];  // per buf: K 4KB + V 4KB

  const int tid = threadIdx.x, lane = tid & 63, w = tid >> 6;  // w in {0,1}
  const int q15 = lane & 15, g = lane >> 4;
  const int bx = blockIdx.x, h = blockIdx.y, b = blockIdx.z;
  const int kh = h >> 2;
  const int QT0 = 63 - bx, QT1 = bx;  // heavy, light q-tiles (32 rows each)

  const char* Qg = (const char*)(Q + ((size_t)(b * 32 + h) * 2048) * 64);
  const char* Kg = (const char*)(Kt + ((size_t)(b * 8 + kh) * 2048 * 64));
  const char* Vg = (const char*)(Vt + ((size_t)(b * 8 + kh) * 64 * 2048));

  // Q fragments (B-operand of swapped QK^T), both tiles
  bf16x8 qf0[2], qf1[2];
#pragma unroll
  for (int ks = 0; ks < 2; ++ks) {
    int r0 = QT0 * 32 + w * 16 + q15;
    int r1 = QT1 * 32 + w * 16 + q15;
    qf0[ks] = *(const bf16x8*)(Qg + (size_t)r0 * 128 + ks * 64 + (g << 4));
    qf1[ks] = *(const bf16x8*)(Qg + (size_t)r1 * 128 + ks * 64 + (g << 4));
  }

  f32x4 acc0[4], acc1[4];
#pragma unroll
  for (int j = 0; j < 4; ++j) {
    acc0[j] = (f32x4){0.f, 0.f, 0.f, 0.f};
    acc1[j] = (f32x4){0.f, 0.f, 0.f, 0.f};
  }
  float m0 = -1e30f, m1 = -1e30f, l0 = 0.f, l1 = 0.f;
  const f32x4 FZ = (f32x4){0.f, 0.f, 0.f, 0.f};

  auto stageKV = [&](int buf, int kt) {
#pragma unroll
    for (int i = 0; i < 2; ++i) {
      int vt = i * 128 + tid;  // 0..255
      // K: LDS row rho holds global kv row kappa(rho) = 8g'+4nf'+r'
      int rho = vt >> 3, ck = vt & 7;
      int kap = ((rho & 12) << 1) + ((rho & 16) >> 2) + (rho & 3);
      gload16(Kg + (size_t)(kt * 32 + kap) * 128 + (((ck ^ rho) & 7) << 4),
              smem + buf * 8192 + vt * 16);
      // V: natural kv order, 64 d-rows x 64B, chunk swizzle ^((d>>1)&3)
      int d = vt >> 2, cv = vt & 3;
      gload16(Vg + (size_t)d * 4096 + kt * 64 + (((cv ^ (d >> 1)) & 3) << 4),
              smem + buf * 8192 + 4096 + vt * 16);
    }
  };

  stageKV(0, 0);
  int cur = 0;
  const int nkt = QT0 + 1;
  for (int kt = 0; kt < nkt; ++kt) {
    __syncthreads();  // KV[cur] staged (compiler drains vmcnt before barrier)
    if (kt + 1 < nkt) stageKV(cur ^ 1, kt + 1);
    const char* Ks = smem + cur * 8192;
    const char* Vs = smem + cur * 8192 + 4096;
    const bool la = (kt <= QT1);  // light tile active

    // K fragments (A-operand), shared by both tiles
    bf16x8 kf[2][2];  // [ks][nf]
#pragma unroll
    for (int ks = 0; ks < 2; ++ks)
#pragma unroll
      for (int nf = 0; nf < 2; ++nf) {
        int r = nf * 16 + q15;
        int c = (4 * ks + g) ^ (r & 7);
        kf[ks][nf] = *(const bf16x8*)(Ks + r * 128 + (c << 4));
      }

    // swapped QK^T: lane holds S[q = Qt*32+w*16+q15][k = kt*32 + 8g+4nf+r]
    f32x4 st0[2], st1[2];
    __builtin_amdgcn_s_setprio(1);
#pragma unroll
    for (int nf = 0; nf < 2; ++nf) {
      st0[nf] = mfma16(kf[0][nf], qf0[0], FZ);
      st0[nf] = mfma16(kf[1][nf], qf0[1], st0[nf]);
    }
    if (la) {
#pragma unroll
      for (int nf = 0; nf < 2; ++nf) {
        st1[nf] = mfma16(kf[0][nf], qf1[0], FZ);
        st1[nf] = mfma16(kf[1][nf], qf1[1], st1[nf]);
      }
    }
    __builtin_amdgcn_s_setprio(0);

    // causal mask on each tile's diagonal step (k = kt*32 + 8g + 4nf + r)
    if (kt == QT0) {
      int qg = QT0 * 32 + w * 16 + q15;
#pragma unroll
      for (int nf = 0; nf < 2; ++nf)
#pragma unroll
        for (int r = 0; r < 4; ++r) {
          int kg = kt * 32 + 8 * g + 4 * nf + r;
          if (kg > qg) st0[nf][r] = -1e30f;
        }
    }
    if (la && kt == QT1) {
      int qg = QT1 * 32 + w * 16 + q15;
#pragma unroll
      for (int nf = 0; nf < 2; ++nf)
#pragma unroll
        for (int r = 0; r < 4; ++r) {
          int kg = kt * 32 + 8 * g + 4 * nf + r;
          if (kg > qg) st1[nf][r] = -1e30f;
        }
    }

    // softmax (exp2 domain, T13 defer-rescale); P packs straight into the
    // K=32 A-fragment: register j = 4nf+r -> k = 8g+j.
    bf16x8 pa0, pa1;
#pragma unroll
    for (int t = 0; t < 2; ++t) {
      if (t == 1 && !la) break;
      f32x4* st = (t == 0) ? st0 : st1;
      float& m_r = (t == 0) ? m0 : m1;
      float& l_r = (t == 0) ? l0 : l1;
      f32x4* accT = (t == 0) ? acc0 : acc1;

      float vm = fmaxf(fmaxf(fmaxf(st[0][0], st[0][1]), fmaxf(st[0][2], st[0][3])),
                       fmaxf(fmaxf(st[1][0], st[1][1]), fmaxf(st[1][2], st[1][3])));
      vm = fmaxf(vm, __shfl_xor(vm, 16, 64));
      vm = fmaxf(vm, __shfl_xor(vm, 32, 64));
      const bool resc = !__all(vm - m_r <= 8.0f);
      if (resc) {
        float mn = fmaxf(m_r, vm);
        float cr = EXP2(m_r - mn);
        m_r = mn;
        l_r *= cr;
        float cra[4];
#pragma unroll
        for (int r = 0; r < 4; ++r) cra[r] = __shfl(cr, 4 * g + r, 64);
#pragma unroll
        for (int nfd = 0; nfd < 4; ++nfd)
#pragma unroll
          for (int r = 0; r < 4; ++r) accT[nfd][r] *= cra[r];
      }
      float vs = 0.f;
      u32x4 W;
      {
        float p0 = EXP2(st[0][0] - m_r), p1 = EXP2(st[0][1] - m_r);
        float p2 = EXP2(st[0][2] - m_r), p3 = EXP2(st[0][3] - m_r);
        float p4 = EXP2(st[1][0] - m_r), p5 = EXP2(st[1][1] - m_r);
        float p6 = EXP2(st[1][2] - m_r), p7 = EXP2(st[1][3] - m_r);
        vs = ((p0 + p1) + (p2 + p3)) + ((p4 + p5) + (p6 + p7));
        W.x = pk2bf(p0, p1);
        W.y = pk2bf(p2, p3);
        W.z = pk2bf(p4, p5);
        W.w = pk2bf(p6, p7);
      }
      if (t == 0) pa0 = __builtin_bit_cast(bf16x8, W);
      else pa1 = __builtin_bit_cast(bf16x8, W);
      vs += __shfl_xor(vs, 16, 64);
      vs += __shfl_xor(vs, 32, 64);
      l_r += vs;
    }

    // PV via K=32 MFMA: B-frag = V^T[d = nfd*16+q15][k = kt*32 + 8g..8g+7],
    // one b128 per nfd (swizzled chunk), natural kv order.
#pragma unroll
    for (int nfd = 0; nfd < 4; ++nfd) {
      int d = nfd * 16 + q15;
      int c = (g ^ (d >> 1)) & 3;
      bf16x8 vb = *(const bf16x8*)(Vs + d * 64 + (c << 4));
      __builtin_amdgcn_s_setprio(1);
      acc0[nfd] = mfma16(pa0, vb, acc0[nfd]);
      if (la) acc1[nfd] = mfma16(pa1, vb, acc1[nfd]);
      __builtin_amdgcn_s_setprio(0);
    }
    cur ^= 1;
  }

  // epilogue: normalize (l lives at q = lane&15; acc rows at q' = 4g+r)
#pragma unroll
  for (int t = 0; t < 2; ++t) {
    float l_r = (t == 0) ? l0 : l1;
    f32x4* accT = (t == 0) ? acc0 : acc1;
    int qt = (t == 0) ? QT0 : QT1;
    u16* Og = O + ((size_t)(b * 2048 + qt * 32 + w * 16) * 2048 + h * 64);
    float la4[4];
#pragma unroll
    for (int r = 0; r < 4; ++r) la4[r] = __shfl(l_r, 4 * g + r, 64);
#pragma unroll
    for (int r = 0; r < 4; ++r) {
      float li = 1.f / la4[r];
#pragma unroll
      for (int nfd = 0; nfd < 4; ++nfd)
        Og[(size_t)(4 * g + r) * 2048 + nfd * 16 + q15] = f2bf(accT[nfd][r] * li);
    }
  }
}

// ---------------------------------------------------------------------------
extern "C" void kernel_launch(void* const* d_in, const int* in_sizes, int n_in,
                              void* d_out, int out_size, void* d_ws, size_t ws_size,
                              hipStream_t stream) {
  const float* x = (const float*)d_in[0];
  const float* fc = (const float*)d_in[1];
  const float* fs = (const float*)d_in[2];
  const float* wq = (const float*)d_in[3];
  const float* wk = (const float*)d_in[4];
  const float* wv = (const float*)d_in[5];
  const float* wo = (const float*)d_in[6];
  float* out = (float*)d_out;
  char* ws = (char*)d_ws;

  // Compact workspace layout (60 MB total):
  u16* xb    = (u16*)(ws);                 // [4096][2048] 16 MB  (reused as Q)
  u16* qkv   = (u16*)(ws + 16777216);      // [4096][3072] 24 MB  (reused as O)
  u16* woT   = (u16*)(ws + 41943040);      // [2048][2048]  8 MB
  u16* wqkvT = (u16*)(ws + 50331648);      // [3072][2048] 12 MB (dead after QKV GEMM)
  u16* Kbuf  = (u16*)(ws + 50331648);      // [2][8][2048][64] 4 MB (overlays wqkvT)
  u16* Vtb   = (u16*)(ws + 54525952);      // [2][8][64][2048] 4 MB (overlays wqkvT)
  u16* Qbuf = xb;
  u16* Obuf = qkv;

  dim3 tb(32, 8);
  cvt_x<<<dim3(8192), dim3(256), 0, stream>>>(x, xb);
  tconv<<<dim3(64, 64), tb, 0, stream>>>(wq, wqkvT, 2048, 0, 2048);
  tconv<<<dim3(16, 64), tb, 0, stream>>>(wk, wqkvT, 512, 2048, 2048);
  tconv<<<dim3(16, 64), tb, 0, stream>>>(wv, wqkvT, 512, 2560, 2048);
  tconv<<<dim3(64, 64), tb, 0, stream>>>(wo, woT, 2048, 0, 2048);
  gemm_bt<u16><<<dim3(24, 32), dim3(256), 0, stream>>>(xb, wqkvT, qkv, 4096, 3072, 2048);
  rope_qk<<<dim3(20480), dim3(256), 0, stream>>>(qkv, fc, fs, Qbuf, Kbuf);
  vtrans<<<dim3(64, 2, 16), tb, 0, stream>>>(qkv, Vtb);
  attn<<<dim3(32, 32, 2), dim3(128), 0, stream>>>(Qbuf, Kbuf, Vtb, Obuf);
  gemm_bt<float><<<dim3(16, 32), dim3(256), 0, stream>>>(Obuf, woT, out, 4096, 2048, 2048);
}